// Round 1
// baseline (1256.082 us; speedup 1.0000x reference)
//
#include <hip/hip_runtime.h>

#define NN 50000
#define NE 800000
#define D_IN 128
#define D_H 256
#define D_OUT 64
#define NG 64

__device__ __forceinline__ float lrelu(float x){ return x > 0.f ? x : 0.2f*x; }

// sortable-uint encoding for float atomicMax
__device__ __forceinline__ unsigned f2sort(float f){
  unsigned b = __float_as_uint(f);
  return (b & 0x80000000u) ? ~b : (b | 0x80000000u);
}
__device__ __forceinline__ float sort2f(unsigned u){
  unsigned b = (u & 0x80000000u) ? (u ^ 0x80000000u) : ~u;
  return __uint_as_float(b);
}

// ---------------- CSR build ----------------
__global__ void count_deg(const int* __restrict__ dst, int* __restrict__ deg){
  int e = blockIdx.x*256 + threadIdx.x;
  if (e < NE) atomicAdd(&deg[dst[e]], 1);
}

__global__ __launch_bounds__(1024) void scan_kernel(const int* __restrict__ deg,
                                                    int* __restrict__ offs,
                                                    int* __restrict__ cursor){
  __shared__ int sums[1024];
  int t = threadIdx.x;
  const int per = (NN + 1023) / 1024;   // 49
  int base = t * per;
  int local = 0;
  for (int i = 0; i < per; i++){ int idx = base + i; if (idx < NN) local += deg[idx]; }
  sums[t] = local;
  __syncthreads();
  for (int off = 1; off < 1024; off <<= 1){
    int v = (t >= off) ? sums[t - off] : 0;
    __syncthreads();
    sums[t] += v;
    __syncthreads();
  }
  int run = sums[t] - local;   // exclusive prefix
  for (int i = 0; i < per; i++){
    int idx = base + i;
    if (idx < NN){ offs[idx] = run; cursor[idx] = run; run += deg[idx]; }
  }
  if (t == 1023) offs[NN] = run;
}

__global__ void scatter_csr(const int* __restrict__ src, const int* __restrict__ dst,
                            int* __restrict__ cursor, int* __restrict__ csr_src){
  int e = blockIdx.x*256 + threadIdx.x;
  if (e < NE){
    int d = dst[e];
    int pos = atomicAdd(&cursor[d], 1);
    csr_src[pos] = src[e];
  }
}

// ---------------- GEMM: C[M,256] = A[M,K] @ B[K,256] ----------------
template<int K>
__global__ __launch_bounds__(256) void gemm_kernel(const float* __restrict__ A,
                                                   const float* __restrict__ B,
                                                   float* __restrict__ C){
  __shared__ float As[16][68];
  __shared__ float Bs[16][68];
  const int t  = threadIdx.x;
  const int bm = blockIdx.x * 64;
  const int bn = blockIdx.y * 64;
  const int tc = t & 15, tr = t >> 4;
  float acc[4][4];
  #pragma unroll
  for (int i = 0; i < 4; i++)
    #pragma unroll
    for (int j = 0; j < 4; j++) acc[i][j] = 0.f;

  const int lk  = t & 15;   // A stage: k
  const int lm  = t >> 4;   // A stage: row base
  const int ln  = t & 63;   // B stage: col
  const int lk2 = t >> 6;   // B stage: k base

  for (int k0 = 0; k0 < K; k0 += 16){
    #pragma unroll
    for (int i = 0; i < 4; i++){
      int m = lm + i*16;
      int row = bm + m;
      As[lk][m] = (row < NN) ? A[row*K + k0 + lk] : 0.f;
    }
    #pragma unroll
    for (int i = 0; i < 4; i++){
      int k = lk2 + i*4;
      Bs[k][ln] = B[(k0 + k)*256 + bn + ln];
    }
    __syncthreads();
    #pragma unroll
    for (int k = 0; k < 16; k++){
      float4 av = *(const float4*)&As[k][tr*4];
      float4 bv = *(const float4*)&Bs[k][tc*4];
      float a[4] = {av.x, av.y, av.z, av.w};
      float b[4] = {bv.x, bv.y, bv.z, bv.w};
      #pragma unroll
      for (int i = 0; i < 4; i++)
        #pragma unroll
        for (int j = 0; j < 4; j++)
          acc[i][j] += a[i] * b[j];
    }
    __syncthreads();
  }
  #pragma unroll
  for (int i = 0; i < 4; i++){
    int row = bm + tr*4 + i;
    if (row < NN){
      float4 v = make_float4(acc[i][0], acc[i][1], acc[i][2], acc[i][3]);
      *(float4*)&C[row*256 + bn + tc*4] = v;
    }
  }
}

// ---------------- s = h@a_src, d = h@a_dst ----------------
__global__ __launch_bounds__(256) void sd_kernel(const float* __restrict__ h,
                                                 const float* __restrict__ a_src,
                                                 const float* __restrict__ a_dst,
                                                 float* __restrict__ s, float* __restrict__ d){
  int wid  = (blockIdx.x * 256 + threadIdx.x) >> 6;
  int lane = threadIdx.x & 63;
  if (wid >= NN) return;
  float4 hv = ((const float4*)h)[wid*64 + lane];
  float4 as = ((const float4*)a_src)[lane];
  float4 ad = ((const float4*)a_dst)[lane];
  float ps = hv.x*as.x + hv.y*as.y + hv.z*as.z + hv.w*as.w;
  float pd = hv.x*ad.x + hv.y*ad.y + hv.z*ad.z + hv.w*ad.w;
  #pragma unroll
  for (int o = 32; o > 0; o >>= 1){
    ps += __shfl_down(ps, o);
    pd += __shfl_down(pd, o);
  }
  if (lane == 0){ s[wid] = ps; d[wid] = pd; }
}

// ---------------- edge passes (E real edges + NN self loops) ----------------
__global__ void edge_max(const int* __restrict__ src, const int* __restrict__ dst,
                         const float* __restrict__ s, const float* __restrict__ d,
                         unsigned* __restrict__ m_u){
  int e = blockIdx.x*256 + threadIdx.x;
  if (e >= NE + NN) return;
  int si, di;
  if (e < NE){ si = src[e]; di = dst[e]; } else { si = di = e - NE; }
  float v = lrelu(s[si] + d[di]);
  atomicMax(&m_u[di], f2sort(v));
}

__global__ void edge_den(const int* __restrict__ src, const int* __restrict__ dst,
                         const float* __restrict__ s, const float* __restrict__ d,
                         const unsigned* __restrict__ m_u, float* __restrict__ den){
  int e = blockIdx.x*256 + threadIdx.x;
  if (e >= NE + NN) return;
  int si, di;
  if (e < NE){ si = src[e]; di = dst[e]; } else { si = di = e - NE; }
  float v = lrelu(s[si] + d[di]);
  float m = sort2f(m_u[di]);
  atomicAdd(&den[di], expf(v - m));
}

// ---------------- aggregation: one wave per dst node ----------------
__global__ __launch_bounds__(256) void agg_kernel(const float* __restrict__ h_in,
                                                  const int* __restrict__ offs,
                                                  const int* __restrict__ csr_src,
                                                  const float* __restrict__ s,
                                                  const float* __restrict__ d,
                                                  const unsigned* __restrict__ m_u,
                                                  const float* __restrict__ den,
                                                  const float* __restrict__ bias,
                                                  float* __restrict__ h_out){
  int node = blockIdx.x*4 + (threadIdx.x >> 6);
  int lane = threadIdx.x & 63;
  if (node >= NN) return;
  float m_i     = sort2f(m_u[node]);
  float inv_den = 1.f / den[node];
  float d_i     = d[node];
  const float4* h4 = (const float4*)h_in;

  // self loop
  float w0 = expf(lrelu(s[node] + d_i) - m_i) * inv_den;
  float4 hv = h4[node*64 + lane];
  float4 acc;
  acc.x = w0*hv.x; acc.y = w0*hv.y; acc.z = w0*hv.z; acc.w = w0*hv.w;

  int beg = offs[node], end = offs[node+1];
  for (int j0 = beg; j0 < end; j0 += 64){
    int j = j0 + lane;
    int sj = 0; float w = 0.f;
    if (j < end){
      sj = csr_src[j];
      w = expf(lrelu(s[sj] + d_i) - m_i) * inv_den;
    }
    int cnt = min(64, end - j0);
    for (int tt = 0; tt < cnt; tt++){
      int   st = __shfl(sj, tt);
      float wt = __shfl(w,  tt);
      float4 hh = h4[st*64 + lane];
      acc.x += wt*hh.x; acc.y += wt*hh.y; acc.z += wt*hh.z; acc.w += wt*hh.w;
    }
  }
  float4 bb = ((const float4*)bias)[lane];
  acc.x = fmaxf(acc.x + bb.x, 0.f);
  acc.y = fmaxf(acc.y + bb.y, 0.f);
  acc.z = fmaxf(acc.z + bb.z, 0.f);
  acc.w = fmaxf(acc.w + bb.w, 0.f);
  ((float4*)h_out)[node*64 + lane] = acc;
}

// ---------------- global add pool (batch sorted) ----------------
__device__ __forceinline__ int lbound(const int* a, int n, int v){
  int lo = 0, hi = n;
  while (lo < hi){ int mid = (lo + hi) >> 1; if (a[mid] < v) lo = mid + 1; else hi = mid; }
  return lo;
}

__global__ __launch_bounds__(256) void pool_kernel(const float* __restrict__ h,
                                                   const int* __restrict__ batch,
                                                   float* __restrict__ pooled){
  int g = blockIdx.x, split = blockIdx.y, t = threadIdx.x;
  int lo = lbound(batch, NN, g);
  int hi = lbound(batch, NN, g + 1);
  int len = hi - lo;
  int chunk = (len + 7) >> 3;
  int b  = lo + split*chunk;
  int e2 = min(hi, b + chunk);
  float acc = 0.f;
  for (int i = b; i < e2; i++) acc += h[i*D_H + t];
  atomicAdd(&pooled[g*D_H + t], acc);
}

// ---------------- final FC: [64,256] @ [256,64] + b ----------------
__global__ __launch_bounds__(64) void fc_kernel(const float* __restrict__ pooled,
                                                const float* __restrict__ fcW,
                                                const float* __restrict__ fcb,
                                                float* __restrict__ out){
  int g = blockIdx.x, o = threadIdx.x;
  float acc = fcb[o];
  for (int k = 0; k < D_H; k++) acc += pooled[g*D_H + k] * fcW[k*D_OUT + o];
  out[g*D_OUT + o] = acc;
}

extern "C" void kernel_launch(void* const* d_in, const int* in_sizes, int n_in,
                              void* d_out, int out_size, void* d_ws, size_t ws_size,
                              hipStream_t stream){
  const float* x     = (const float*)d_in[0];
  const int*   ei    = (const int*)d_in[1];
  const int*   batch = (const int*)d_in[2];
  const float* W1  = (const float*)d_in[3];
  const float* as1 = (const float*)d_in[4];
  const float* ad1 = (const float*)d_in[5];
  const float* b1  = (const float*)d_in[6];
  const float* W2  = (const float*)d_in[7];
  const float* as2 = (const float*)d_in[8];
  const float* ad2 = (const float*)d_in[9];
  const float* b2  = (const float*)d_in[10];
  const float* W3  = (const float*)d_in[11];
  const float* as3 = (const float*)d_in[12];
  const float* ad3 = (const float*)d_in[13];
  const float* b3  = (const float*)d_in[14];
  const float* fcW = (const float*)d_in[15];
  const float* fcb = (const float*)d_in[16];

  const int* src = ei;
  const int* dst = ei + NE;

  float* ws   = (float*)d_ws;
  float* h_a  = ws;                       // 12,800,000
  float* h_b  = h_a + 12800000;           // 12,800,000
  float* sbuf = h_b + 12800000;           // 50,000
  float* dbuf = sbuf + NN;                // 50,000
  float* den  = dbuf + NN;                // 50,000
  unsigned* m_u = (unsigned*)(den + NN);  // 50,000
  int* deg    = (int*)(m_u + NN);         // 50,000
  int* offs   = deg + NN;                 // 50,016 (uses 50,001)
  int* cursor = offs + 50016;             // 50,000
  int* csr    = cursor + NN;              // 800,000
  float* pooled = (float*)(csr + NE);     // 16,384

  // CSR build (once per launch)
  hipMemsetAsync(deg, 0, NN*sizeof(int), stream);
  count_deg<<<(NE + 255)/256, 256, 0, stream>>>(dst, deg);
  scan_kernel<<<1, 1024, 0, stream>>>(deg, offs, cursor);
  scatter_csr<<<(NE + 255)/256, 256, 0, stream>>>(src, dst, cursor, csr);
  hipMemsetAsync(pooled, 0, NG*D_H*sizeof(float), stream);

  const float* Ws[3]  = {W1, W2, W3};
  const float* asr[3] = {as1, as2, as3};
  const float* adt[3] = {ad1, ad2, ad3};
  const float* bs[3]  = {b1, b2, b3};

  const int egrid = (NE + NN + 255)/256;
  for (int L = 0; L < 3; L++){
    const float* in = (L == 0) ? x : h_b;
    if (L == 0) gemm_kernel<128><<<dim3(782, 4), 256, 0, stream>>>(in, Ws[L], h_a);
    else        gemm_kernel<256><<<dim3(782, 4), 256, 0, stream>>>(in, Ws[L], h_a);
    sd_kernel<<<12500, 256, 0, stream>>>(h_a, asr[L], adt[L], sbuf, dbuf);
    hipMemsetAsync(den, 0, NN*2*sizeof(float), stream);   // den + m_u contiguous
    edge_max<<<egrid, 256, 0, stream>>>(src, dst, sbuf, dbuf, m_u);
    edge_den<<<egrid, 256, 0, stream>>>(src, dst, sbuf, dbuf, m_u, den);
    agg_kernel<<<12500, 256, 0, stream>>>(h_a, offs, csr, sbuf, dbuf, m_u, den, bs[L], h_b);
  }
  pool_kernel<<<dim3(NG, 8), 256, 0, stream>>>(h_b, batch, pooled);
  fc_kernel<<<NG, 64, 0, stream>>>(pooled, fcW, fcb, (float*)d_out);
}

// Round 2
// 591.119 us; speedup vs baseline: 2.1249x; 2.1249x over previous
//
#include <hip/hip_runtime.h>

#define NN 50000
#define NE 800000
#define D_IN 128
#define D_H 256
#define D_OUT 64
#define NG 64

typedef short bf16x8 __attribute__((ext_vector_type(8)));
typedef float f32x4 __attribute__((ext_vector_type(4)));

__device__ __forceinline__ float lrelu(float x){ return x > 0.f ? x : 0.2f*x; }

__device__ __forceinline__ unsigned short f2b(float f){
  unsigned u = __float_as_uint(f);
  unsigned r = (u + 0x7FFFu + ((u >> 16) & 1u)) >> 16;   // RNE
  return (unsigned short)r;
}
__device__ __forceinline__ float b2f(unsigned short h){
  return __uint_as_float(((unsigned)h) << 16);
}

// ---------------- casts ----------------
__global__ __launch_bounds__(256) void cast_x_kernel(const float* __restrict__ x,
                                                     unsigned short* __restrict__ xb){
  int gid = blockIdx.x*256 + threadIdx.x;          // one float4 per thread
  if (gid >= NN*D_IN/4) return;
  float4 v = ((const float4*)x)[gid];
  ushort4 o = { f2b(v.x), f2b(v.y), f2b(v.z), f2b(v.w) };
  ((ushort4*)xb)[gid] = o;
}

__global__ __launch_bounds__(256) void cast_wt_kernel(const float* __restrict__ W,  // [K][256]
                                                      unsigned short* __restrict__ Wt, // [256][K]
                                                      int K){
  int e = blockIdx.x*256 + threadIdx.x;            // grid = K blocks
  int n = e & 255, k = e >> 8;
  Wt[n*K + k] = f2b(W[e]);
}

// ---------------- CSR build ----------------
__global__ void count_deg(const int* __restrict__ dst, int* __restrict__ deg){
  int e = blockIdx.x*256 + threadIdx.x;
  if (e < NE) atomicAdd(&deg[dst[e]], 1);
}

__global__ __launch_bounds__(256) void scan_bsum(const int* __restrict__ deg,
                                                 int* __restrict__ bsum){
  __shared__ int sm[256];
  int b = blockIdx.x, t = threadIdx.x;
  int gid = b*256 + t;
  sm[t] = (gid < NN) ? deg[gid] : 0;
  __syncthreads();
  for (int off = 128; off > 0; off >>= 1){
    if (t < off) sm[t] += sm[t+off];
    __syncthreads();
  }
  if (t == 0) bsum[b] = sm[0];
}

__global__ __launch_bounds__(256) void scan_offs(const int* __restrict__ deg,
                                                 const int* __restrict__ bsum,
                                                 int* __restrict__ offs,
                                                 int* __restrict__ cursor,
                                                 int nblk){
  __shared__ int sb[256];
  __shared__ int sm[256];
  int b = blockIdx.x, t = threadIdx.x;
  sb[t] = (t < nblk) ? bsum[t] : 0;
  __syncthreads();
  for (int off = 1; off < 256; off <<= 1){
    int v = (t >= off) ? sb[t-off] : 0;
    __syncthreads();
    sb[t] += v;
    __syncthreads();
  }
  int base = (b == 0) ? 0 : sb[b-1];
  int gid = b*256 + t;
  int v = (gid < NN) ? deg[gid] : 0;
  sm[t] = v;
  __syncthreads();
  for (int off = 1; off < 256; off <<= 1){
    int u = (t >= off) ? sm[t-off] : 0;
    __syncthreads();
    sm[t] += u;
    __syncthreads();
  }
  int incl = sm[t], excl = incl - v;
  if (gid < NN){ offs[gid] = base + excl; cursor[gid] = base + excl; }
  if (gid == NN-1) offs[NN] = base + incl;
}

__global__ void scatter_csr(const int* __restrict__ src, const int* __restrict__ dst,
                            int* __restrict__ cursor, int* __restrict__ csr_src){
  int e = blockIdx.x*256 + threadIdx.x;
  if (e < NE){
    int d = dst[e];
    int pos = atomicAdd(&cursor[d], 1);
    csr_src[pos] = src[e];
  }
}

// ---------------- bf16 MFMA GEMM: C16[M,256] = A[M,K] @ B[K,256] ----------------
// A bf16 row-major [M][K]; Wt bf16 [256][K] (pre-transposed); C16 bf16 [NN][256]
template<int K>
__global__ __launch_bounds__(256) void gemm_bf16(const unsigned short* __restrict__ A,
                                                 const unsigned short* __restrict__ Wt,
                                                 unsigned short* __restrict__ C16){
  __shared__ unsigned short As[128*72];   // stride 72 halves = 144B (16B-aligned, 2-way banks)
  const int t = threadIdx.x;
  const int bm = blockIdx.x * 128;
  const int bn = blockIdx.y * 128;
  const int wave = t >> 6, lane = t & 63;
  const int wm = (wave >> 1) * 64, wn = (wave & 1) * 64;
  const int l15 = lane & 15, quad = lane >> 4;

  f32x4 acc[4][4];
  #pragma unroll
  for (int i = 0; i < 4; i++)
    #pragma unroll
    for (int j = 0; j < 4; j++){
      f32x4 z = {0.f, 0.f, 0.f, 0.f};
      acc[i][j] = z;
    }

  for (int k0 = 0; k0 < K; k0 += 32){
    #pragma unroll
    for (int i = 0; i < 2; i++){
      int c = t + i*256;                 // 0..511
      int m = c >> 2, ko = (c & 3) * 8;
      int row = bm + m;
      bf16x8 v = {0,0,0,0,0,0,0,0};
      if (row < NN) v = *(const bf16x8*)(A + (size_t)row*K + k0 + ko);
      *(bf16x8*)(&As[m*72 + ko]) = v;
    }
    __syncthreads();
    bf16x8 af[4];
    #pragma unroll
    for (int i = 0; i < 4; i++)
      af[i] = *(const bf16x8*)(&As[(wm + i*16 + l15)*72 + quad*8]);
    #pragma unroll
    for (int j = 0; j < 4; j++){
      int n = bn + wn + j*16 + l15;
      bf16x8 bfr = *(const bf16x8*)(Wt + (size_t)n*K + k0 + quad*8);
      #pragma unroll
      for (int i = 0; i < 4; i++)
        acc[i][j] = __builtin_amdgcn_mfma_f32_16x16x32_bf16(af[i], bfr, acc[i][j], 0, 0, 0);
    }
    __syncthreads();
  }
  #pragma unroll
  for (int i = 0; i < 4; i++){
    #pragma unroll
    for (int r = 0; r < 4; r++){
      int row = bm + wm + i*16 + quad*4 + r;
      if (row < NN){
        #pragma unroll
        for (int j = 0; j < 4; j++){
          int col = bn + wn + j*16 + l15;
          C16[(size_t)row*256 + col] = f2b(acc[i][j][r]);
        }
      }
    }
  }
}

// ---------------- s = h@a_src, d = h@a_dst (h in bf16) ----------------
__global__ __launch_bounds__(256) void sd_kernel(const unsigned short* __restrict__ h16,
                                                 const float* __restrict__ a_src,
                                                 const float* __restrict__ a_dst,
                                                 float* __restrict__ s, float* __restrict__ d){
  int wid  = (blockIdx.x * 256 + threadIdx.x) >> 6;
  int lane = threadIdx.x & 63;
  if (wid >= NN) return;
  ushort4 hv = ((const ushort4*)h16)[(size_t)wid*64 + lane];
  float4 as = ((const float4*)a_src)[lane];
  float4 ad = ((const float4*)a_dst)[lane];
  float hx = b2f(hv.x), hy = b2f(hv.y), hz = b2f(hv.z), hw = b2f(hv.w);
  float ps = hx*as.x + hy*as.y + hz*as.z + hw*as.w;
  float pd = hx*ad.x + hy*ad.y + hz*ad.z + hw*ad.w;
  #pragma unroll
  for (int o = 32; o > 0; o >>= 1){
    ps += __shfl_down(ps, o);
    pd += __shfl_down(pd, o);
  }
  if (lane == 0){ s[wid] = ps; d[wid] = pd; }
}

// ---------------- fused softmax + aggregation: one wave per dst node ----------------
__global__ __launch_bounds__(256) void agg_kernel(const unsigned short* __restrict__ h16,
                                                  const int* __restrict__ offs,
                                                  const int* __restrict__ csr_src,
                                                  const float* __restrict__ s,
                                                  const float* __restrict__ d,
                                                  const float* __restrict__ bias,
                                                  float* __restrict__ hout,
                                                  unsigned short* __restrict__ hout16){
  int node = blockIdx.x*4 + (threadIdx.x >> 6);
  int lane = threadIdx.x & 63;
  if (node >= NN) return;
  float d_i = d[node];
  int beg = offs[node], end = offs[node+1];

  // online softmax over incoming edges (per lane, then merge)
  float m_l = -1e30f, s_l = 0.f;
  for (int j0 = beg; j0 < end; j0 += 64){
    int j = j0 + lane;
    if (j < end){
      int sj = csr_src[j];
      float e = lrelu(s[sj] + d_i);
      float nm = fmaxf(m_l, e);
      s_l = s_l*__expf(m_l - nm) + __expf(e - nm);
      m_l = nm;
    }
  }
  #pragma unroll
  for (int off = 32; off > 0; off >>= 1){
    float om = __shfl_xor(m_l, off);
    float os = __shfl_xor(s_l, off);
    float nm = fmaxf(m_l, om);
    s_l = s_l*__expf(m_l - nm) + os*__expf(om - nm);
    m_l = nm;
  }
  // self loop
  float e0 = lrelu(s[node] + d_i);
  float m_i = fmaxf(m_l, e0);
  float den = s_l*__expf(m_l - m_i) + __expf(e0 - m_i);
  float inv_den = 1.f / den;

  const ushort4* h4 = (const ushort4*)h16;
  float w0 = __expf(e0 - m_i) * inv_den;
  ushort4 hv = h4[(size_t)node*64 + lane];
  float4 acc;
  acc.x = w0*b2f(hv.x); acc.y = w0*b2f(hv.y); acc.z = w0*b2f(hv.z); acc.w = w0*b2f(hv.w);

  for (int j0 = beg; j0 < end; j0 += 64){
    int j = j0 + lane;
    int sj = 0; float w = 0.f;
    if (j < end){
      sj = csr_src[j];
      w = __expf(lrelu(s[sj] + d_i) - m_i) * inv_den;
    }
    int cnt = min(64, end - j0);
    for (int tt = 0; tt < cnt; tt++){
      int   st = __shfl(sj, tt);
      float wt = __shfl(w,  tt);
      ushort4 hh = h4[(size_t)st*64 + lane];
      acc.x += wt*b2f(hh.x); acc.y += wt*b2f(hh.y);
      acc.z += wt*b2f(hh.z); acc.w += wt*b2f(hh.w);
    }
  }
  float4 bb = ((const float4*)bias)[lane];
  acc.x = fmaxf(acc.x + bb.x, 0.f);
  acc.y = fmaxf(acc.y + bb.y, 0.f);
  acc.z = fmaxf(acc.z + bb.z, 0.f);
  acc.w = fmaxf(acc.w + bb.w, 0.f);
  ((float4*)hout)[(size_t)node*64 + lane] = acc;
  ushort4 o16 = { f2b(acc.x), f2b(acc.y), f2b(acc.z), f2b(acc.w) };
  ((ushort4*)hout16)[(size_t)node*64 + lane] = o16;
}

// ---------------- global add pool (batch sorted) ----------------
__device__ __forceinline__ int lbound(const int* a, int n, int v){
  int lo = 0, hi = n;
  while (lo < hi){ int mid = (lo + hi) >> 1; if (a[mid] < v) lo = mid + 1; else hi = mid; }
  return lo;
}

__global__ __launch_bounds__(256) void pool_kernel(const float* __restrict__ h,
                                                   const int* __restrict__ batch,
                                                   float* __restrict__ pooled){
  int g = blockIdx.x, split = blockIdx.y, t = threadIdx.x;
  int lo = lbound(batch, NN, g);
  int hi = lbound(batch, NN, g + 1);
  int len = hi - lo;
  int chunk = (len + 7) >> 3;
  int b  = lo + split*chunk;
  int e2 = min(hi, b + chunk);
  float acc = 0.f;
  for (int i = b; i < e2; i++) acc += h[(size_t)i*D_H + t];
  atomicAdd(&pooled[g*D_H + t], acc);
}

// ---------------- final FC: [64,256] @ [256,64] + b ----------------
__global__ __launch_bounds__(64) void fc_kernel(const float* __restrict__ pooled,
                                                const float* __restrict__ fcW,
                                                const float* __restrict__ fcb,
                                                float* __restrict__ out){
  int g = blockIdx.x, o = threadIdx.x;
  float acc = fcb[o];
  for (int k = 0; k < D_H; k++) acc += pooled[g*D_H + k] * fcW[k*D_OUT + o];
  out[g*D_OUT + o] = acc;
}

extern "C" void kernel_launch(void* const* d_in, const int* in_sizes, int n_in,
                              void* d_out, int out_size, void* d_ws, size_t ws_size,
                              hipStream_t stream){
  const float* x     = (const float*)d_in[0];
  const int*   ei    = (const int*)d_in[1];
  const int*   batch = (const int*)d_in[2];
  const float* W1  = (const float*)d_in[3];
  const float* as1 = (const float*)d_in[4];
  const float* ad1 = (const float*)d_in[5];
  const float* b1  = (const float*)d_in[6];
  const float* W2  = (const float*)d_in[7];
  const float* as2 = (const float*)d_in[8];
  const float* ad2 = (const float*)d_in[9];
  const float* b2  = (const float*)d_in[10];
  const float* W3  = (const float*)d_in[11];
  const float* as3 = (const float*)d_in[12];
  const float* ad3 = (const float*)d_in[13];
  const float* b3  = (const float*)d_in[14];
  const float* fcW = (const float*)d_in[15];
  const float* fcb = (const float*)d_in[16];

  const int* src = ei;
  const int* dst = ei + NE;

  // bump allocator on d_ws (>=256 MiB available)
  char* p = (char*)d_ws;
  auto alloc = [&](size_t bytes) -> void* {
    void* r = (void*)p;
    p += (bytes + 255) & ~(size_t)255;
    return r;
  };
  float* h_b            = (float*)alloc((size_t)NN*D_H*4);   // fp32 post-agg (pool input)
  unsigned short* h_a16 = (unsigned short*)alloc((size_t)NN*D_H*2);
  unsigned short* h_b16 = (unsigned short*)alloc((size_t)NN*D_H*2);
  unsigned short* xb    = (unsigned short*)alloc((size_t)NN*D_IN*2);
  unsigned short* Wt0   = (unsigned short*)alloc((size_t)256*D_IN*2);
  unsigned short* Wt1   = (unsigned short*)alloc((size_t)256*256*2);
  unsigned short* Wt2   = (unsigned short*)alloc((size_t)256*256*2);
  float* sbuf   = (float*)alloc((size_t)NN*4);
  float* dbuf   = (float*)alloc((size_t)NN*4);
  int* deg      = (int*)alloc((size_t)NN*4);
  int* offs     = (int*)alloc((size_t)(NN+1)*4);
  int* cursor   = (int*)alloc((size_t)NN*4);
  int* bsum     = (int*)alloc((size_t)256*4);
  int* csr      = (int*)alloc((size_t)NE*4);
  float* pooled = (float*)alloc((size_t)NG*D_H*4);

  const int nblk = (NN + 255)/256;   // 196

  // CSR build
  hipMemsetAsync(deg, 0, NN*sizeof(int), stream);
  count_deg<<<(NE + 255)/256, 256, 0, stream>>>(dst, deg);
  scan_bsum<<<nblk, 256, 0, stream>>>(deg, bsum);
  scan_offs<<<nblk, 256, 0, stream>>>(deg, bsum, offs, cursor, nblk);
  scatter_csr<<<(NE + 255)/256, 256, 0, stream>>>(src, dst, cursor, csr);
  hipMemsetAsync(pooled, 0, NG*D_H*sizeof(float), stream);

  // casts
  cast_x_kernel<<<(NN*D_IN/4 + 255)/256, 256, 0, stream>>>(x, xb);
  cast_wt_kernel<<<D_IN, 256, 0, stream>>>(W1, Wt0, D_IN);
  cast_wt_kernel<<<256, 256, 0, stream>>>(W2, Wt1, 256);
  cast_wt_kernel<<<256, 256, 0, stream>>>(W3, Wt2, 256);

  const unsigned short* Wts[3] = {Wt0, Wt1, Wt2};
  const float* asr[3] = {as1, as2, as3};
  const float* adt[3] = {ad1, ad2, ad3};
  const float* bs[3]  = {b1, b2, b3};

  const int mgrid = (NN + 127)/128;   // 391
  for (int L = 0; L < 3; L++){
    if (L == 0) gemm_bf16<128><<<dim3(mgrid, 2), 256, 0, stream>>>(xb, Wts[0], h_a16);
    else        gemm_bf16<256><<<dim3(mgrid, 2), 256, 0, stream>>>(h_b16, Wts[L], h_a16);
    sd_kernel<<<(NN*64 + 255)/256, 256, 0, stream>>>(h_a16, asr[L], adt[L], sbuf, dbuf);
    agg_kernel<<<(NN + 3)/4, 256, 0, stream>>>(h_a16, offs, csr, sbuf, dbuf, bs[L], h_b, h_b16);
  }
  pool_kernel<<<dim3(NG, 8), 256, 0, stream>>>(h_b, batch, pooled);
  fc_kernel<<<NG, 64, 0, stream>>>(pooled, fcW, fcb, (float*)d_out);
}

// Round 3
// 573.838 us; speedup vs baseline: 2.1889x; 1.0301x over previous
//
#include <hip/hip_runtime.h>

#define NN 50000
#define NE 800000
#define D_IN 128
#define D_H 256
#define D_OUT 64
#define NG 64

typedef short bf16x8 __attribute__((ext_vector_type(8)));
typedef unsigned short u16x8 __attribute__((ext_vector_type(8)));
typedef float f32x4 __attribute__((ext_vector_type(4)));

__device__ __forceinline__ float lrelu(float x){ return x > 0.f ? x : 0.2f*x; }

__device__ __forceinline__ unsigned short f2b(float f){
  unsigned u = __float_as_uint(f);
  unsigned r = (u + 0x7FFFu + ((u >> 16) & 1u)) >> 16;   // RNE
  return (unsigned short)r;
}
__device__ __forceinline__ float b2f(unsigned short h){
  return __uint_as_float(((unsigned)h) << 16);
}

// ---------------- casts ----------------
__global__ __launch_bounds__(256) void cast_x_kernel(const float* __restrict__ x,
                                                     unsigned short* __restrict__ xb){
  int gid = blockIdx.x*256 + threadIdx.x;          // one float4 per thread
  if (gid >= NN*D_IN/4) return;
  float4 v = ((const float4*)x)[gid];
  ushort4 o = { f2b(v.x), f2b(v.y), f2b(v.z), f2b(v.w) };
  ((ushort4*)xb)[gid] = o;
}

__global__ __launch_bounds__(256) void cast_wt_kernel(const float* __restrict__ W,  // [K][256]
                                                      unsigned short* __restrict__ Wt, // [256][K]
                                                      int K){
  int e = blockIdx.x*256 + threadIdx.x;            // grid = K blocks
  int n = e & 255, k = e >> 8;
  Wt[n*K + k] = f2b(W[e]);
}

// ---------------- CSR build ----------------
__global__ void count_deg(const int* __restrict__ dst, int* __restrict__ deg){
  int e = blockIdx.x*256 + threadIdx.x;
  if (e < NE) atomicAdd(&deg[dst[e]], 1);
}

__global__ __launch_bounds__(256) void scan_bsum(const int* __restrict__ deg,
                                                 int* __restrict__ bsum){
  __shared__ int sm[256];
  int b = blockIdx.x, t = threadIdx.x;
  int gid = b*256 + t;
  sm[t] = (gid < NN) ? deg[gid] : 0;
  __syncthreads();
  for (int off = 128; off > 0; off >>= 1){
    if (t < off) sm[t] += sm[t+off];
    __syncthreads();
  }
  if (t == 0) bsum[b] = sm[0];
}

__global__ __launch_bounds__(256) void scan_offs(const int* __restrict__ deg,
                                                 const int* __restrict__ bsum,
                                                 int* __restrict__ offs,
                                                 int* __restrict__ cursor,
                                                 int nblk){
  __shared__ int sb[256];
  __shared__ int sm[256];
  int b = blockIdx.x, t = threadIdx.x;
  sb[t] = (t < nblk) ? bsum[t] : 0;
  __syncthreads();
  for (int off = 1; off < 256; off <<= 1){
    int v = (t >= off) ? sb[t-off] : 0;
    __syncthreads();
    sb[t] += v;
    __syncthreads();
  }
  int base = (b == 0) ? 0 : sb[b-1];
  int gid = b*256 + t;
  int v = (gid < NN) ? deg[gid] : 0;
  sm[t] = v;
  __syncthreads();
  for (int off = 1; off < 256; off <<= 1){
    int u = (t >= off) ? sm[t-off] : 0;
    __syncthreads();
    sm[t] += u;
    __syncthreads();
  }
  int incl = sm[t], excl = incl - v;
  if (gid < NN){ offs[gid] = base + excl; cursor[gid] = base + excl; }
  if (gid == NN-1) offs[NN] = base + incl;
}

__global__ void scatter_csr(const int* __restrict__ src, const int* __restrict__ dst,
                            int* __restrict__ cursor, int* __restrict__ csr_src){
  int e = blockIdx.x*256 + threadIdx.x;
  if (e < NE){
    int d = dst[e];
    int pos = atomicAdd(&cursor[d], 1);
    csr_src[pos] = src[e];
  }
}

// ---------------- bf16 MFMA GEMM: C16[M,256] = A[M,K] @ B[K,256] ----------------
template<int K>
__global__ __launch_bounds__(256) void gemm_bf16(const unsigned short* __restrict__ A,
                                                 const unsigned short* __restrict__ Wt,
                                                 unsigned short* __restrict__ C16){
  __shared__ unsigned short As[128*72];   // stride 72 halves = 144B
  const int t = threadIdx.x;
  const int bm = blockIdx.x * 128;
  const int bn = blockIdx.y * 128;
  const int wave = t >> 6, lane = t & 63;
  const int wm = (wave >> 1) * 64, wn = (wave & 1) * 64;
  const int l15 = lane & 15, quad = lane >> 4;

  f32x4 acc[4][4];
  #pragma unroll
  for (int i = 0; i < 4; i++)
    #pragma unroll
    for (int j = 0; j < 4; j++){
      f32x4 z = {0.f, 0.f, 0.f, 0.f};
      acc[i][j] = z;
    }

  for (int k0 = 0; k0 < K; k0 += 32){
    #pragma unroll
    for (int i = 0; i < 2; i++){
      int c = t + i*256;                 // 0..511
      int m = c >> 2, ko = (c & 3) * 8;
      int row = bm + m;
      bf16x8 v = {0,0,0,0,0,0,0,0};
      if (row < NN) v = *(const bf16x8*)(A + (size_t)row*K + k0 + ko);
      *(bf16x8*)(&As[m*72 + ko]) = v;
    }
    __syncthreads();
    bf16x8 af[4];
    #pragma unroll
    for (int i = 0; i < 4; i++)
      af[i] = *(const bf16x8*)(&As[(wm + i*16 + l15)*72 + quad*8]);
    #pragma unroll
    for (int j = 0; j < 4; j++){
      int n = bn + wn + j*16 + l15;
      bf16x8 bfr = *(const bf16x8*)(Wt + (size_t)n*K + k0 + quad*8);
      #pragma unroll
      for (int i = 0; i < 4; i++)
        acc[i][j] = __builtin_amdgcn_mfma_f32_16x16x32_bf16(af[i], bfr, acc[i][j], 0, 0, 0);
    }
    __syncthreads();
  }
  #pragma unroll
  for (int i = 0; i < 4; i++){
    #pragma unroll
    for (int r = 0; r < 4; r++){
      int row = bm + wm + i*16 + quad*4 + r;
      if (row < NN){
        #pragma unroll
        for (int j = 0; j < 4; j++){
          int col = bn + wn + j*16 + l15;
          C16[(size_t)row*256 + col] = f2b(acc[i][j][r]);
        }
      }
    }
  }
}

// ---------------- s = h@a_src, d = h@a_dst (h in bf16) ----------------
__global__ __launch_bounds__(256) void sd_kernel(const unsigned short* __restrict__ h16,
                                                 const float* __restrict__ a_src,
                                                 const float* __restrict__ a_dst,
                                                 float* __restrict__ s, float* __restrict__ d){
  int wid  = (blockIdx.x * 256 + threadIdx.x) >> 6;
  int lane = threadIdx.x & 63;
  if (wid >= NN) return;
  ushort4 hv = ((const ushort4*)h16)[(size_t)wid*64 + lane];
  float4 as = ((const float4*)a_src)[lane];
  float4 ad = ((const float4*)a_dst)[lane];
  float hx = b2f(hv.x), hy = b2f(hv.y), hz = b2f(hv.z), hw = b2f(hv.w);
  float ps = hx*as.x + hy*as.y + hz*as.z + hw*as.w;
  float pd = hx*ad.x + hy*ad.y + hz*ad.z + hw*ad.w;
  #pragma unroll
  for (int o = 32; o > 0; o >>= 1){
    ps += __shfl_down(ps, o);
    pd += __shfl_down(pd, o);
  }
  if (lane == 0){ s[wid] = ps; d[wid] = pd; }
}

// ---------------- fused softmax + aggregation: one wave per dst node ----------------
// half = lane>>5 picks edge slot; c = lane&31 picks 16B feature chunk.
// 4 edges per iteration (2 per half), 2 independent dwordx4 loads in flight.
__global__ __launch_bounds__(256) void agg_kernel(const unsigned short* __restrict__ h16,
                                                  const int* __restrict__ offs,
                                                  const int* __restrict__ csr_src,
                                                  const float* __restrict__ s,
                                                  const float* __restrict__ d,
                                                  const float* __restrict__ bias,
                                                  float* __restrict__ hout32,
                                                  unsigned short* __restrict__ hout16,
                                                  int write32){
  int node = blockIdx.x*4 + (threadIdx.x >> 6);
  int lane = threadIdx.x & 63;
  if (node >= NN) return;
  float d_i = d[node];
  int beg = offs[node], end = offs[node+1];

  // pass 1: online softmax stats, 64-lane edge-parallel
  float m_l = -1e30f, s_l = 0.f;
  for (int j = beg + lane; j < end; j += 64){
    int sj = csr_src[j];
    float e = lrelu(s[sj] + d_i);
    float nm = fmaxf(m_l, e);
    s_l = s_l*__expf(m_l - nm) + __expf(e - nm);
    m_l = nm;
  }
  #pragma unroll
  for (int off = 32; off > 0; off >>= 1){
    float om = __shfl_xor(m_l, off);
    float os = __shfl_xor(s_l, off);
    float nm = fmaxf(m_l, om);
    s_l = s_l*__expf(m_l - nm) + os*__expf(om - nm);
    m_l = nm;
  }
  float e0 = lrelu(s[node] + d_i);               // self loop
  float m_i = fmaxf(m_l, e0);
  float inv_den = 1.f / (s_l*__expf(m_l - m_i) + __expf(e0 - m_i));

  const int half = lane >> 5;
  const int c    = lane & 31;
  const u16x8* h8 = (const u16x8*)h16;           // row stride = 32 chunks

  float acc[8];
  #pragma unroll
  for (int i = 0; i < 8; i++) acc[i] = 0.f;

  if (half == 0){                                // self loop (half 0 only; halves summed later)
    float w0 = __expf(e0 - m_i) * inv_den;
    u16x8 hv = h8[(size_t)node*32 + c];
    #pragma unroll
    for (int i = 0; i < 8; i++) acc[i] += w0 * b2f(hv[i]);
  }

  for (int eb = beg; eb < end; eb += 4){
    int e1 = eb + half;
    int e2 = e1 + 2;
    int sa = csr_src[min(e1, end-1)];
    int sb = csr_src[min(e2, end-1)];
    float wa = (e1 < end) ? __expf(lrelu(s[sa] + d_i) - m_i) * inv_den : 0.f;
    float wb = (e2 < end) ? __expf(lrelu(s[sb] + d_i) - m_i) * inv_den : 0.f;
    u16x8 ha = h8[(size_t)sa*32 + c];
    u16x8 hb = h8[(size_t)sb*32 + c];
    #pragma unroll
    for (int i = 0; i < 8; i++) acc[i] += wa * b2f(ha[i]);
    #pragma unroll
    for (int i = 0; i < 8; i++) acc[i] += wb * b2f(hb[i]);
  }

  // merge halves
  #pragma unroll
  for (int i = 0; i < 8; i++) acc[i] += __shfl_xor(acc[i], 32);

  // bias + relu
  const float4* bb = (const float4*)(bias + c*8);
  float4 b0 = bb[0], b1 = bb[1];
  acc[0] = fmaxf(acc[0] + b0.x, 0.f); acc[1] = fmaxf(acc[1] + b0.y, 0.f);
  acc[2] = fmaxf(acc[2] + b0.z, 0.f); acc[3] = fmaxf(acc[3] + b0.w, 0.f);
  acc[4] = fmaxf(acc[4] + b1.x, 0.f); acc[5] = fmaxf(acc[5] + b1.y, 0.f);
  acc[6] = fmaxf(acc[6] + b1.z, 0.f); acc[7] = fmaxf(acc[7] + b1.w, 0.f);

  if (half == 0){
    u16x8 o;
    #pragma unroll
    for (int i = 0; i < 8; i++) o[i] = f2b(acc[i]);
    ((u16x8*)hout16)[(size_t)node*32 + c] = o;
  } else if (write32){
    float4 v0 = make_float4(acc[0], acc[1], acc[2], acc[3]);
    float4 v1 = make_float4(acc[4], acc[5], acc[6], acc[7]);
    ((float4*)hout32)[(size_t)node*64 + c*2]     = v0;
    ((float4*)hout32)[(size_t)node*64 + c*2 + 1] = v1;
  }
}

// ---------------- global add pool (batch sorted) ----------------
__device__ __forceinline__ int lbound(const int* a, int n, int v){
  int lo = 0, hi = n;
  while (lo < hi){ int mid = (lo + hi) >> 1; if (a[mid] < v) lo = mid + 1; else hi = mid; }
  return lo;
}

__global__ __launch_bounds__(256) void pool_kernel(const float* __restrict__ h,
                                                   const int* __restrict__ batch,
                                                   float* __restrict__ pooled){
  int g = blockIdx.x, split = blockIdx.y, t = threadIdx.x;
  int lo = lbound(batch, NN, g);
  int hi = lbound(batch, NN, g + 1);
  int len = hi - lo;
  int chunk = (len + 7) >> 3;
  int b  = lo + split*chunk;
  int e2 = min(hi, b + chunk);
  float acc = 0.f;
  for (int i = b; i < e2; i++) acc += h[(size_t)i*D_H + t];
  atomicAdd(&pooled[g*D_H + t], acc);
}

// ---------------- final FC: [64,256] @ [256,64] + b ----------------
__global__ __launch_bounds__(64) void fc_kernel(const float* __restrict__ pooled,
                                                const float* __restrict__ fcW,
                                                const float* __restrict__ fcb,
                                                float* __restrict__ out){
  int g = blockIdx.x, o = threadIdx.x;
  float acc = fcb[o];
  for (int k = 0; k < D_H; k++) acc += pooled[g*D_H + k] * fcW[k*D_OUT + o];
  out[g*D_OUT + o] = acc;
}

extern "C" void kernel_launch(void* const* d_in, const int* in_sizes, int n_in,
                              void* d_out, int out_size, void* d_ws, size_t ws_size,
                              hipStream_t stream){
  const float* x     = (const float*)d_in[0];
  const int*   ei    = (const int*)d_in[1];
  const int*   batch = (const int*)d_in[2];
  const float* W1  = (const float*)d_in[3];
  const float* as1 = (const float*)d_in[4];
  const float* ad1 = (const float*)d_in[5];
  const float* b1  = (const float*)d_in[6];
  const float* W2  = (const float*)d_in[7];
  const float* as2 = (const float*)d_in[8];
  const float* ad2 = (const float*)d_in[9];
  const float* b2  = (const float*)d_in[10];
  const float* W3  = (const float*)d_in[11];
  const float* as3 = (const float*)d_in[12];
  const float* ad3 = (const float*)d_in[13];
  const float* b3  = (const float*)d_in[14];
  const float* fcW = (const float*)d_in[15];
  const float* fcb = (const float*)d_in[16];

  const int* src = ei;
  const int* dst = ei + NE;

  char* p = (char*)d_ws;
  auto alloc = [&](size_t bytes) -> void* {
    void* r = (void*)p;
    p += (bytes + 255) & ~(size_t)255;
    return r;
  };
  float* h_b            = (float*)alloc((size_t)NN*D_H*4);   // fp32 final-layer h (pool input)
  unsigned short* h_a16 = (unsigned short*)alloc((size_t)NN*D_H*2);
  unsigned short* h_b16 = (unsigned short*)alloc((size_t)NN*D_H*2);
  unsigned short* xb    = (unsigned short*)alloc((size_t)NN*D_IN*2);
  unsigned short* Wt0   = (unsigned short*)alloc((size_t)256*D_IN*2);
  unsigned short* Wt1   = (unsigned short*)alloc((size_t)256*256*2);
  unsigned short* Wt2   = (unsigned short*)alloc((size_t)256*256*2);
  float* sbuf   = (float*)alloc((size_t)NN*4);
  float* dbuf   = (float*)alloc((size_t)NN*4);
  int* deg      = (int*)alloc((size_t)NN*4);
  int* offs     = (int*)alloc((size_t)(NN+1)*4);
  int* cursor   = (int*)alloc((size_t)NN*4);
  int* bsum     = (int*)alloc((size_t)256*4);
  int* csr      = (int*)alloc((size_t)NE*4);
  float* pooled = (float*)alloc((size_t)NG*D_H*4);

  const int nblk = (NN + 255)/256;   // 196

  // CSR build
  hipMemsetAsync(deg, 0, NN*sizeof(int), stream);
  count_deg<<<(NE + 255)/256, 256, 0, stream>>>(dst, deg);
  scan_bsum<<<nblk, 256, 0, stream>>>(deg, bsum);
  scan_offs<<<nblk, 256, 0, stream>>>(deg, bsum, offs, cursor, nblk);
  scatter_csr<<<(NE + 255)/256, 256, 0, stream>>>(src, dst, cursor, csr);
  hipMemsetAsync(pooled, 0, NG*D_H*sizeof(float), stream);

  // casts
  cast_x_kernel<<<(NN*D_IN/4 + 255)/256, 256, 0, stream>>>(x, xb);
  cast_wt_kernel<<<D_IN, 256, 0, stream>>>(W1, Wt0, D_IN);
  cast_wt_kernel<<<256, 256, 0, stream>>>(W2, Wt1, 256);
  cast_wt_kernel<<<256, 256, 0, stream>>>(W3, Wt2, 256);

  const unsigned short* Wts[3] = {Wt0, Wt1, Wt2};
  const float* asr[3] = {as1, as2, as3};
  const float* adt[3] = {ad1, ad2, ad3};
  const float* bs[3]  = {b1, b2, b3};

  const int mgrid = (NN + 127)/128;   // 391
  for (int L = 0; L < 3; L++){
    if (L == 0) gemm_bf16<128><<<dim3(mgrid, 2), 256, 0, stream>>>(xb, Wts[0], h_a16);
    else        gemm_bf16<256><<<dim3(mgrid, 2), 256, 0, stream>>>(h_b16, Wts[L], h_a16);
    sd_kernel<<<(NN*64 + 255)/256, 256, 0, stream>>>(h_a16, asr[L], adt[L], sbuf, dbuf);
    agg_kernel<<<(NN + 3)/4, 256, 0, stream>>>(h_a16, offs, csr, sbuf, dbuf, bs[L],
                                               h_b, h_b16, (L == 2) ? 1 : 0);
  }
  pool_kernel<<<dim3(NG, 8), 256, 0, stream>>>(h_b, batch, pooled);
  fc_kernel<<<NG, 64, 0, stream>>>(pooled, fcW, fcb, (float*)d_out);
}

// Round 4
// 501.688 us; speedup vs baseline: 2.5037x; 1.1438x over previous
//
#include <hip/hip_runtime.h>

#define NN 50000
#define NE 800000
#define D_IN 128
#define D_H 256
#define D_OUT 64
#define NG 64
#define MAXD 100   // fast-path degree cap (LDS slots = 104)

typedef short bf16x8 __attribute__((ext_vector_type(8)));
typedef unsigned short u16x8 __attribute__((ext_vector_type(8)));
typedef float f32x4 __attribute__((ext_vector_type(4)));

__device__ __forceinline__ float lrelu(float x){ return x > 0.f ? x : 0.2f*x; }

__device__ __forceinline__ unsigned short f2b(float f){
  unsigned u = __float_as_uint(f);
  unsigned r = (u + 0x7FFFu + ((u >> 16) & 1u)) >> 16;   // RNE
  return (unsigned short)r;
}
__device__ __forceinline__ float b2f(unsigned short h){
  return __uint_as_float(((unsigned)h) << 16);
}

// ---------------- casts ----------------
__global__ __launch_bounds__(256) void cast_x_kernel(const float* __restrict__ x,
                                                     unsigned short* __restrict__ xb){
  int gid = blockIdx.x*256 + threadIdx.x;          // one float4 per thread
  if (gid >= NN*D_IN/4) return;
  float4 v = ((const float4*)x)[gid];
  ushort4 o = { f2b(v.x), f2b(v.y), f2b(v.z), f2b(v.w) };
  ((ushort4*)xb)[gid] = o;
}

// W [K][256] row-major -> Wt packed in MFMA B-fragment order:
// group g = (n>>4)*(K>>5) + (k>>5); within-group half index = (((k>>3)&3)*16 + (n&15))*8 + (k&7)
__device__ __forceinline__ void cast_one_wt(const float* W, unsigned short* Wt, int K, int idx){
  int k = idx >> 8, n = idx & 255;
  int grp = (n >> 4)*(K >> 5) + (k >> 5);
  int within = ((((k >> 3) & 3) << 4) | (n & 15)) * 8 + (k & 7);
  Wt[grp*512 + within] = f2b(W[idx]);
}

__global__ __launch_bounds__(256) void cast_wt_all(const float* __restrict__ W1,
                                                   const float* __restrict__ W2,
                                                   const float* __restrict__ W3,
                                                   unsigned short* __restrict__ Wt0,
                                                   unsigned short* __restrict__ Wt1,
                                                   unsigned short* __restrict__ Wt2){
  int e = blockIdx.x*256 + threadIdx.x;            // 32768 + 65536 + 65536 = 163840
  if (e < 32768)        cast_one_wt(W1, Wt0, 128, e);
  else if (e < 98304)   cast_one_wt(W2, Wt1, 256, e - 32768);
  else                  cast_one_wt(W3, Wt2, 256, e - 98304);
}

// ---------------- CSR build ----------------
__global__ void count_deg(const int* __restrict__ dst, int* __restrict__ deg){
  int e = blockIdx.x*256 + threadIdx.x;
  if (e < NE) atomicAdd(&deg[dst[e]], 1);
}

__global__ __launch_bounds__(256) void scan_bsum(const int* __restrict__ deg,
                                                 int* __restrict__ bsum){
  __shared__ int sm[256];
  int b = blockIdx.x, t = threadIdx.x;
  int gid = b*256 + t;
  sm[t] = (gid < NN) ? deg[gid] : 0;
  __syncthreads();
  for (int off = 128; off > 0; off >>= 1){
    if (t < off) sm[t] += sm[t+off];
    __syncthreads();
  }
  if (t == 0) bsum[b] = sm[0];
}

__global__ __launch_bounds__(256) void scan_offs(const int* __restrict__ deg,
                                                 const int* __restrict__ bsum,
                                                 int* __restrict__ offs,
                                                 int* __restrict__ cursor,
                                                 int nblk){
  __shared__ int sb[256];
  __shared__ int sm[256];
  int b = blockIdx.x, t = threadIdx.x;
  sb[t] = (t < nblk) ? bsum[t] : 0;
  __syncthreads();
  for (int off = 1; off < 256; off <<= 1){
    int v = (t >= off) ? sb[t-off] : 0;
    __syncthreads();
    sb[t] += v;
    __syncthreads();
  }
  int base = (b == 0) ? 0 : sb[b-1];
  int gid = b*256 + t;
  int v = (gid < NN) ? deg[gid] : 0;
  sm[t] = v;
  __syncthreads();
  for (int off = 1; off < 256; off <<= 1){
    int u = (t >= off) ? sm[t-off] : 0;
    __syncthreads();
    sm[t] += u;
    __syncthreads();
  }
  int incl = sm[t], excl = incl - v;
  if (gid < NN){ offs[gid] = base + excl; cursor[gid] = base + excl; }
  if (gid == NN-1) offs[NN] = base + incl;
}

__global__ void scatter_csr(const int* __restrict__ src, const int* __restrict__ dst,
                            int* __restrict__ cursor, int* __restrict__ csr_src){
  int e = blockIdx.x*256 + threadIdx.x;
  if (e < NE){
    int d = dst[e];
    int pos = atomicAdd(&cursor[d], 1);
    csr_src[pos] = src[e];
  }
}

// ---------------- bf16 MFMA GEMM: C16[M,256] = A[M,K] @ B[K,256] ----------------
// Wt is packed in fragment order (see cast_one_wt).
template<int K>
__global__ __launch_bounds__(256) void gemm_bf16(const unsigned short* __restrict__ A,
                                                 const unsigned short* __restrict__ Wt,
                                                 unsigned short* __restrict__ C16){
  __shared__ unsigned short As[128*72];   // stride 72 halves = 144B
  const int t = threadIdx.x;
  const int bm = blockIdx.x * 128;
  const int bn = blockIdx.y * 128;
  const int wave = t >> 6, lane = t & 63;
  const int wm = (wave >> 1) * 64, wn = (wave & 1) * 64;
  const int l15 = lane & 15, quad = lane >> 4;

  f32x4 acc[4][4];
  #pragma unroll
  for (int i = 0; i < 4; i++)
    #pragma unroll
    for (int j = 0; j < 4; j++){
      f32x4 z = {0.f, 0.f, 0.f, 0.f};
      acc[i][j] = z;
    }

  for (int k0 = 0; k0 < K; k0 += 32){
    #pragma unroll
    for (int i = 0; i < 2; i++){
      int c = t + i*256;                 // 0..511
      int m = c >> 2, ko = (c & 3) * 8;
      int row = bm + m;
      bf16x8 v = {0,0,0,0,0,0,0,0};
      if (row < NN) v = *(const bf16x8*)(A + (size_t)row*K + k0 + ko);
      *(bf16x8*)(&As[m*72 + ko]) = v;
    }
    __syncthreads();
    bf16x8 af[4];
    #pragma unroll
    for (int i = 0; i < 4; i++)
      af[i] = *(const bf16x8*)(&As[(wm + i*16 + l15)*72 + quad*8]);
    const int ks = k0 >> 5;
    #pragma unroll
    for (int j = 0; j < 4; j++){
      int nb = ((bn + wn) >> 4) + j;
      bf16x8 bfr = *(const bf16x8*)(Wt + ((size_t)(nb*(K>>5) + ks))*512 + lane*8);
      #pragma unroll
      for (int i = 0; i < 4; i++)
        acc[i][j] = __builtin_amdgcn_mfma_f32_16x16x32_bf16(af[i], bfr, acc[i][j], 0, 0, 0);
    }
    __syncthreads();
  }
  #pragma unroll
  for (int i = 0; i < 4; i++){
    #pragma unroll
    for (int r = 0; r < 4; r++){
      int row = bm + wm + i*16 + quad*4 + r;
      if (row < NN){
        #pragma unroll
        for (int j = 0; j < 4; j++){
          int col = bn + wn + j*16 + l15;
          C16[(size_t)row*256 + col] = f2b(acc[i][j][r]);
        }
      }
    }
  }
}

// ---------------- s = h@a_src, d = h@a_dst (h in bf16) ----------------
__global__ __launch_bounds__(256) void sd_kernel(const unsigned short* __restrict__ h16,
                                                 const float* __restrict__ a_src,
                                                 const float* __restrict__ a_dst,
                                                 float* __restrict__ s, float* __restrict__ d){
  int wid  = (blockIdx.x * 256 + threadIdx.x) >> 6;
  int lane = threadIdx.x & 63;
  if (wid >= NN) return;
  ushort4 hv = ((const ushort4*)h16)[(size_t)wid*64 + lane];
  float4 as = ((const float4*)a_src)[lane];
  float4 ad = ((const float4*)a_dst)[lane];
  float hx = b2f(hv.x), hy = b2f(hv.y), hz = b2f(hv.z), hw = b2f(hv.w);
  float ps = hx*as.x + hy*as.y + hz*as.z + hw*as.w;
  float pd = hx*ad.x + hy*ad.y + hz*ad.z + hw*ad.w;
  #pragma unroll
  for (int o = 32; o > 0; o >>= 1){
    ps += __shfl_down(ps, o);
    pd += __shfl_down(pd, o);
  }
  if (lane == 0){ s[wid] = ps; d[wid] = pd; }
}

// ---------------- fused softmax + aggregation: one wave per dst node ----------------
// Pass A: edge-parallel e_j -> LDS {src, e}; online m/den. Pass B: LDS e -> weight
// (self-loop appended as an extra slot, padded to x4 with w=0). Gather loop: half-split,
// ds_read_b64 meta -> one dependent dwordx4 row gather. No __syncthreads (per-wave LDS).
__global__ __launch_bounds__(256) void agg_kernel(const unsigned short* __restrict__ h16,
                                                  const int* __restrict__ offs,
                                                  const int* __restrict__ csr_src,
                                                  const float* __restrict__ s,
                                                  const float* __restrict__ d,
                                                  const float* __restrict__ bias,
                                                  unsigned short* __restrict__ hout16){
  __shared__ int2 meta[4][MAXD + 4];
  const int wv = threadIdx.x >> 6;
  const int node = blockIdx.x*4 + wv;
  const int lane = threadIdx.x & 63;
  if (node >= NN) return;
  const float d_i = d[node];
  const int beg = offs[node], end = offs[node+1];
  const int deg = end - beg;
  const bool fast = (deg <= MAXD);          // wave-uniform

  // pass A: e_j, online softmax stats
  float m_l = -1e30f, s_l = 0.f;
  for (int j = lane; j < deg; j += 64){
    int sj = csr_src[beg + j];
    float e = lrelu(s[sj] + d_i);
    if (fast) meta[wv][j] = make_int2(sj, __float_as_int(e));
    float nm = fmaxf(m_l, e);
    s_l = s_l*__expf(m_l - nm) + __expf(e - nm);
    m_l = nm;
  }
  #pragma unroll
  for (int off = 32; off > 0; off >>= 1){
    float om = __shfl_xor(m_l, off);
    float os = __shfl_xor(s_l, off);
    float nm = fmaxf(m_l, om);
    s_l = s_l*__expf(m_l - nm) + os*__expf(om - nm);
    m_l = nm;
  }
  const float e0 = lrelu(s[node] + d_i);    // self loop
  const float m_i = fmaxf(m_l, e0);
  const float inv_den = 1.f / (s_l*__expf(m_l - m_i) + __expf(e0 - m_i));
  const float w0 = __expf(e0 - m_i) * inv_den;

  const int half = lane >> 5;
  const int c    = lane & 31;
  const u16x8* h8 = (const u16x8*)h16;      // row = 32 chunks of 16B

  float acc[8];
  #pragma unroll
  for (int i = 0; i < 8; i++) acc[i] = 0.f;

  if (fast){
    const int n_s = deg + 1;                // + self loop
    const int np  = (n_s + 3) & ~3;
    // pass B: e -> w, append self, pad
    for (int j = lane; j < np; j += 64){
      int sj; float w;
      if (j < deg){
        int2 mv = meta[wv][j];
        sj = mv.x;
        w = __expf(__int_as_float(mv.y) - m_i) * inv_den;
      } else if (j == deg){ sj = node; w = w0; }
      else { sj = 0; w = 0.f; }
      meta[wv][j] = make_int2(sj, __float_as_int(w));
    }
    // gather: 4 slots per iteration (2 per half)
    for (int eb = 0; eb < np; eb += 4){
      int2 ma = meta[wv][eb + half];
      int2 mb = meta[wv][eb + 2 + half];
      float wa = __int_as_float(ma.y);
      float wb = __int_as_float(mb.y);
      u16x8 ha = h8[(size_t)ma.x*32 + c];
      u16x8 hb = h8[(size_t)mb.x*32 + c];
      #pragma unroll
      for (int i = 0; i < 8; i++) acc[i] += wa * b2f(ha[i]);
      #pragma unroll
      for (int i = 0; i < 8; i++) acc[i] += wb * b2f(hb[i]);
    }
  } else {
    // slow path (deg > MAXD): recompute weights in-loop
    if (half == 0){
      u16x8 hv = h8[(size_t)node*32 + c];
      #pragma unroll
      for (int i = 0; i < 8; i++) acc[i] += w0 * b2f(hv[i]);
    }
    for (int eb = beg; eb < end; eb += 4){
      int e1 = eb + half;
      int e2 = e1 + 2;
      int sa = csr_src[min(e1, end-1)];
      int sb = csr_src[min(e2, end-1)];
      float wa = (e1 < end) ? __expf(lrelu(s[sa] + d_i) - m_i) * inv_den : 0.f;
      float wb = (e2 < end) ? __expf(lrelu(s[sb] + d_i) - m_i) * inv_den : 0.f;
      u16x8 ha = h8[(size_t)sa*32 + c];
      u16x8 hb = h8[(size_t)sb*32 + c];
      #pragma unroll
      for (int i = 0; i < 8; i++) acc[i] += wa * b2f(ha[i]);
      #pragma unroll
      for (int i = 0; i < 8; i++) acc[i] += wb * b2f(hb[i]);
    }
  }

  // merge halves
  #pragma unroll
  for (int i = 0; i < 8; i++) acc[i] += __shfl_xor(acc[i], 32);

  // bias + relu
  const float4* bb = (const float4*)(bias + c*8);
  float4 b0 = bb[0], b1 = bb[1];
  acc[0] = fmaxf(acc[0] + b0.x, 0.f); acc[1] = fmaxf(acc[1] + b0.y, 0.f);
  acc[2] = fmaxf(acc[2] + b0.z, 0.f); acc[3] = fmaxf(acc[3] + b0.w, 0.f);
  acc[4] = fmaxf(acc[4] + b1.x, 0.f); acc[5] = fmaxf(acc[5] + b1.y, 0.f);
  acc[6] = fmaxf(acc[6] + b1.z, 0.f); acc[7] = fmaxf(acc[7] + b1.w, 0.f);

  if (half == 0){
    u16x8 o;
    #pragma unroll
    for (int i = 0; i < 8; i++) o[i] = f2b(acc[i]);
    ((u16x8*)hout16)[(size_t)node*32 + c] = o;
  }
}

// ---------------- global add pool (batch sorted), bf16 input ----------------
__device__ __forceinline__ int lbound(const int* a, int n, int v){
  int lo = 0, hi = n;
  while (lo < hi){ int mid = (lo + hi) >> 1; if (a[mid] < v) lo = mid + 1; else hi = mid; }
  return lo;
}

__global__ __launch_bounds__(256) void pool_kernel(const unsigned short* __restrict__ h16,
                                                   const int* __restrict__ batch,
                                                   float* __restrict__ pooled){
  int g = blockIdx.x, split = blockIdx.y, t = threadIdx.x;
  int lo = lbound(batch, NN, g);
  int hi = lbound(batch, NN, g + 1);
  int len = hi - lo;
  int chunk = (len + 15) >> 4;
  int b  = lo + split*chunk;
  int e2 = min(hi, b + chunk);
  float acc = 0.f;
  for (int i = b; i < e2; i++) acc += b2f(h16[(size_t)i*D_H + t]);
  atomicAdd(&pooled[g*D_H + t], acc);
}

// ---------------- final FC: [64,256] @ [256,64] + b ----------------
__global__ __launch_bounds__(64) void fc_kernel(const float* __restrict__ pooled,
                                                const float* __restrict__ fcW,
                                                const float* __restrict__ fcb,
                                                float* __restrict__ out){
  int g = blockIdx.x, o = threadIdx.x;
  float acc = fcb[o];
  for (int k = 0; k < D_H; k++) acc += pooled[g*D_H + k] * fcW[k*D_OUT + o];
  out[g*D_OUT + o] = acc;
}

extern "C" void kernel_launch(void* const* d_in, const int* in_sizes, int n_in,
                              void* d_out, int out_size, void* d_ws, size_t ws_size,
                              hipStream_t stream){
  const float* x     = (const float*)d_in[0];
  const int*   ei    = (const int*)d_in[1];
  const int*   batch = (const int*)d_in[2];
  const float* W1  = (const float*)d_in[3];
  const float* as1 = (const float*)d_in[4];
  const float* ad1 = (const float*)d_in[5];
  const float* b1  = (const float*)d_in[6];
  const float* W2  = (const float*)d_in[7];
  const float* as2 = (const float*)d_in[8];
  const float* ad2 = (const float*)d_in[9];
  const float* b2  = (const float*)d_in[10];
  const float* W3  = (const float*)d_in[11];
  const float* as3 = (const float*)d_in[12];
  const float* ad3 = (const float*)d_in[13];
  const float* b3  = (const float*)d_in[14];
  const float* fcW = (const float*)d_in[15];
  const float* fcb = (const float*)d_in[16];

  const int* src = ei;
  const int* dst = ei + NE;

  char* p = (char*)d_ws;
  auto alloc = [&](size_t bytes) -> void* {
    void* r = (void*)p;
    p += (bytes + 255) & ~(size_t)255;
    return r;
  };
  unsigned short* h_a16 = (unsigned short*)alloc((size_t)NN*D_H*2);
  unsigned short* h_b16 = (unsigned short*)alloc((size_t)NN*D_H*2);
  unsigned short* xb    = (unsigned short*)alloc((size_t)NN*D_IN*2);
  unsigned short* Wt0   = (unsigned short*)alloc((size_t)256*D_IN*2);
  unsigned short* Wt1   = (unsigned short*)alloc((size_t)256*256*2);
  unsigned short* Wt2   = (unsigned short*)alloc((size_t)256*256*2);
  float* sbuf   = (float*)alloc((size_t)NN*4);
  float* dbuf   = (float*)alloc((size_t)NN*4);
  int* deg      = (int*)alloc((size_t)NN*4);
  int* offs     = (int*)alloc((size_t)(NN+1)*4);
  int* cursor   = (int*)alloc((size_t)NN*4);
  int* bsum     = (int*)alloc((size_t)256*4);
  int* csr      = (int*)alloc((size_t)NE*4);
  float* pooled = (float*)alloc((size_t)NG*D_H*4);

  const int nblk = (NN + 255)/256;   // 196

  // CSR build
  hipMemsetAsync(deg, 0, NN*sizeof(int), stream);
  count_deg<<<(NE + 255)/256, 256, 0, stream>>>(dst, deg);
  scan_bsum<<<nblk, 256, 0, stream>>>(deg, bsum);
  scan_offs<<<nblk, 256, 0, stream>>>(deg, bsum, offs, cursor, nblk);
  scatter_csr<<<(NE + 255)/256, 256, 0, stream>>>(src, dst, cursor, csr);
  hipMemsetAsync(pooled, 0, NG*D_H*sizeof(float), stream);

  // casts
  cast_x_kernel<<<(NN*D_IN/4 + 255)/256, 256, 0, stream>>>(x, xb);
  cast_wt_all<<<640, 256, 0, stream>>>(W1, W2, W3, Wt0, Wt1, Wt2);

  const unsigned short* Wts[3] = {Wt0, Wt1, Wt2};
  const float* asr[3] = {as1, as2, as3};
  const float* adt[3] = {ad1, ad2, ad3};
  const float* bs[3]  = {b1, b2, b3};

  const int mgrid = (NN + 127)/128;   // 391
  for (int L = 0; L < 3; L++){
    if (L == 0) gemm_bf16<128><<<dim3(mgrid, 2), 256, 0, stream>>>(xb, Wts[0], h_a16);
    else        gemm_bf16<256><<<dim3(mgrid, 2), 256, 0, stream>>>(h_b16, Wts[L], h_a16);
    sd_kernel<<<(NN*64 + 255)/256, 256, 0, stream>>>(h_a16, asr[L], adt[L], sbuf, dbuf);
    agg_kernel<<<(NN + 3)/4, 256, 0, stream>>>(h_a16, offs, csr, sbuf, dbuf, bs[L], h_b16);
  }
  pool_kernel<<<dim3(NG, 16), 256, 0, stream>>>(h_b16, batch, pooled);
  fc_kernel<<<NG, 64, 0, stream>>>(pooled, fcW, fcb, (float*)d_out);
}

// Round 5
// 491.095 us; speedup vs baseline: 2.5577x; 1.0216x over previous
//
#include <hip/hip_runtime.h>

#define NN 50000
#define NE 800000
#define D_IN 128
#define D_H 256
#define D_OUT 64
#define NG 64
#define MAXD 100   // fast-path degree cap

typedef short bf16x8 __attribute__((ext_vector_type(8)));
typedef unsigned short u16x8 __attribute__((ext_vector_type(8)));
typedef float f32x4 __attribute__((ext_vector_type(4)));

__device__ __forceinline__ float lrelu(float x){ return x > 0.f ? x : 0.2f*x; }

__device__ __forceinline__ unsigned short f2b(float f){
  unsigned u = __float_as_uint(f);
  unsigned r = (u + 0x7FFFu + ((u >> 16) & 1u)) >> 16;   // RNE
  return (unsigned short)r;
}
__device__ __forceinline__ float b2f(unsigned short h){
  return __uint_as_float(((unsigned)h) << 16);
}

// ---------------- prep: cast x to bf16 + degree count ----------------
__global__ __launch_bounds__(256) void prep_kernel(const float* __restrict__ x,
                                                   unsigned short* __restrict__ xb,
                                                   const int* __restrict__ dst,
                                                   int* __restrict__ deg){
  int gid = blockIdx.x*256 + threadIdx.x;
  if (gid < NN*D_IN/4){
    float4 v = ((const float4*)x)[gid];
    ushort4 o = { f2b(v.x), f2b(v.y), f2b(v.z), f2b(v.w) };
    ((ushort4*)xb)[gid] = o;
  }
  if (gid < NE) atomicAdd(&deg[dst[gid]], 1);
}

// W [K][256] row-major -> Wt packed in MFMA B-fragment order:
// group g = (n>>4)*(K>>5) + (k>>5); within-group half idx = (((k>>3)&3)*16 + (n&15))*8 + (k&7)
__device__ __forceinline__ void cast_one_wt(const float* W, unsigned short* Wt, int K, int idx){
  int k = idx >> 8, n = idx & 255;
  int grp = (n >> 4)*(K >> 5) + (k >> 5);
  int within = ((((k >> 3) & 3) << 4) | (n & 15)) * 8 + (k & 7);
  Wt[grp*512 + within] = f2b(W[idx]);
}

// blocks 0..639: cast W1/W2/W3; blocks 640..642: wv[L] = {W_L @ a_src_L, W_L @ a_dst_L}
__global__ __launch_bounds__(256) void cast_wt_all(const float* __restrict__ W1,
                                                   const float* __restrict__ W2,
                                                   const float* __restrict__ W3,
                                                   const float* __restrict__ as1,
                                                   const float* __restrict__ ad1,
                                                   const float* __restrict__ as2,
                                                   const float* __restrict__ ad2,
                                                   const float* __restrict__ as3,
                                                   const float* __restrict__ ad3,
                                                   unsigned short* __restrict__ Wt0,
                                                   unsigned short* __restrict__ Wt1,
                                                   unsigned short* __restrict__ Wt2,
                                                   float* __restrict__ wv){
  int b = blockIdx.x;
  if (b < 640){
    int e = b*256 + threadIdx.x;            // 32768 + 65536 + 65536
    if (e < 32768)        cast_one_wt(W1, Wt0, 128, e);
    else if (e < 98304)   cast_one_wt(W2, Wt1, 256, e - 32768);
    else                  cast_one_wt(W3, Wt2, 256, e - 98304);
  } else {
    int L = b - 640;
    const float* W  = (L==0) ? W1 : ((L==1) ? W2 : W3);
    const float* av = (L==0) ? as1 : ((L==1) ? as2 : as3);
    const float* dv = (L==0) ? ad1 : ((L==1) ? ad2 : ad3);
    int K   = (L==0) ? 128 : 256;
    int off = (L==0) ? 0 : ((L==1) ? 256 : 768);
    int k = threadIdx.x;
    if (k < K){
      float ps = 0.f, pd = 0.f;
      for (int n = 0; n < 256; n += 4){
        float4 w  = *(const float4*)(W + k*256 + n);
        float4 a  = *(const float4*)(av + n);
        float4 d2 = *(const float4*)(dv + n);
        ps += w.x*a.x + w.y*a.y + w.z*a.z + w.w*a.w;
        pd += w.x*d2.x + w.y*d2.y + w.z*d2.z + w.w*d2.w;
      }
      wv[off + k]     = ps;
      wv[off + K + k] = pd;
    }
  }
}

// ---------------- CSR build ----------------
__global__ __launch_bounds__(256) void scan_bsum(const int* __restrict__ deg,
                                                 int* __restrict__ bsum){
  __shared__ int sm[256];
  int b = blockIdx.x, t = threadIdx.x;
  int gid = b*256 + t;
  sm[t] = (gid < NN) ? deg[gid] : 0;
  __syncthreads();
  for (int off = 128; off > 0; off >>= 1){
    if (t < off) sm[t] += sm[t+off];
    __syncthreads();
  }
  if (t == 0) bsum[b] = sm[0];
}

__global__ __launch_bounds__(256) void scan_offs(const int* __restrict__ deg,
                                                 const int* __restrict__ bsum,
                                                 int* __restrict__ offs,
                                                 int* __restrict__ cursor,
                                                 int nblk){
  __shared__ int sb[256];
  __shared__ int sm[256];
  int b = blockIdx.x, t = threadIdx.x;
  sb[t] = (t < nblk) ? bsum[t] : 0;
  __syncthreads();
  for (int off = 1; off < 256; off <<= 1){
    int v = (t >= off) ? sb[t-off] : 0;
    __syncthreads();
    sb[t] += v;
    __syncthreads();
  }
  int base = (b == 0) ? 0 : sb[b-1];
  int gid = b*256 + t;
  int v = (gid < NN) ? deg[gid] : 0;
  sm[t] = v;
  __syncthreads();
  for (int off = 1; off < 256; off <<= 1){
    int u = (t >= off) ? sm[t-off] : 0;
    __syncthreads();
    sm[t] += u;
    __syncthreads();
  }
  int incl = sm[t], excl = incl - v;
  if (gid < NN){ offs[gid] = base + excl; cursor[gid] = base + excl; }
  if (gid == NN-1) offs[NN] = base + incl;
}

__global__ void scatter_csr(const int* __restrict__ src, const int* __restrict__ dst,
                            int* __restrict__ cursor, int* __restrict__ csr_src){
  int e = blockIdx.x*256 + threadIdx.x;
  if (e < NE){
    int d = dst[e];
    int pos = atomicAdd(&cursor[d], 1);
    csr_src[pos] = src[e];
  }
}

// ---------------- bf16 MFMA GEMM: full-K LDS panel, one barrier, LDS-staged C ----------------
template<int K>
__global__ __launch_bounds__(256) void gemm_bf16(const unsigned short* __restrict__ A,
                                                 const unsigned short* __restrict__ Wt,
                                                 unsigned short* __restrict__ C16){
  constexpr int CH  = K/8;                  // 16B chunks per row
  constexpr int SH  = (K > 132) ? K : 132;  // halves per row (LDS capacity)
  __shared__ unsigned short As[128*SH];
  const int t = threadIdx.x;
  const int bm = blockIdx.x * 128;
  const int bn = blockIdx.y * 128;
  const int wave = t >> 6, lane = t & 63;
  const int wm = (wave >> 1) * 64, wn = (wave & 1) * 64;
  const int l15 = lane & 15, quad = lane >> 4;

  // stage full A panel, chunk-XOR swizzle: physical chunk p = c ^ (row & 7)
  {
    const int c  = t & (CH-1);
    const int r0 = t / CH;
    constexpr int NRG = 256/CH;             // rows per pass (8 or 16)
    const int p = c ^ (r0 & 7);             // row&7 == r0&7 (NRG multiple of 8)
    #pragma unroll
    for (int g = 0; g < 128/NRG; g++){
      int row = r0 + g*NRG;
      int grow = bm + row;
      bf16x8 v = {0,0,0,0,0,0,0,0};
      if (grow < NN) v = *(const bf16x8*)(A + (size_t)grow*K + c*8);
      *(bf16x8*)(&As[row*K + p*8]) = v;
    }
  }
  __syncthreads();

  f32x4 acc[4][4];
  #pragma unroll
  for (int i = 0; i < 4; i++)
    #pragma unroll
    for (int j = 0; j < 4; j++){
      f32x4 z = {0.f, 0.f, 0.f, 0.f};
      acc[i][j] = z;
    }

  #pragma unroll
  for (int ks = 0; ks < K/32; ks++){
    bf16x8 af[4];
    const int pc = ((ks*4 + quad) ^ (l15 & 7)) * 8;
    #pragma unroll
    for (int i = 0; i < 4; i++)
      af[i] = *(const bf16x8*)(&As[(wm + i*16 + l15)*K + pc]);
    #pragma unroll
    for (int j = 0; j < 4; j++){
      int nb = ((bn + wn) >> 4) + j;
      bf16x8 bfr = *(const bf16x8*)(Wt + ((size_t)(nb*(K>>5) + ks))*512 + lane*8);
      #pragma unroll
      for (int i = 0; i < 4; i++)
        acc[i][j] = __builtin_amdgcn_mfma_f32_16x16x32_bf16(af[i], bfr, acc[i][j], 0, 0, 0);
    }
  }

  // epilogue: pack bf16 tile into LDS (stride 132), then coalesced 16B stores
  __syncthreads();
  #pragma unroll
  for (int i = 0; i < 4; i++)
    #pragma unroll
    for (int j = 0; j < 4; j++)
      #pragma unroll
      for (int r = 0; r < 4; r++)
        As[(wm + i*16 + quad*4 + r)*132 + wn + j*16 + l15] = f2b(acc[i][j][r]);
  __syncthreads();
  {
    const int rl = t >> 1, hc = (t & 1)*64;
    const int grow = bm + rl;
    if (grow < NN){
      #pragma unroll
      for (int u = 0; u < 8; u++){
        bf16x8 v = *(const bf16x8*)(&As[rl*132 + hc + u*8]);
        *(bf16x8*)(C16 + (size_t)grow*256 + bn + hc + u*8) = v;
      }
    }
  }
}

// ---------------- s1/d1 = xb @ wv1 (K=128) ----------------
__global__ __launch_bounds__(256) void sd1_kernel(const unsigned short* __restrict__ xb,
                                                  const float* __restrict__ wv,
                                                  float* __restrict__ s, float* __restrict__ d){
  int node = (blockIdx.x*256 + threadIdx.x) >> 6;
  int lane = threadIdx.x & 63;
  if (node >= NN) return;
  ushort2 xv = ((const ushort2*)xb)[(size_t)node*64 + lane];
  float2 ws = ((const float2*)(wv))[lane];
  float2 wd = ((const float2*)(wv + 128))[lane];
  float x0 = b2f(xv.x), x1 = b2f(xv.y);
  float ps = x0*ws.x + x1*ws.y;
  float pd = x0*wd.x + x1*wd.y;
  #pragma unroll
  for (int o = 32; o > 0; o >>= 1){
    ps += __shfl_down(ps, o);
    pd += __shfl_down(pd, o);
  }
  if (lane == 0){ s[node] = ps; d[node] = pd; }
}

// ---------------- fused softmax + aggregation + next-layer s/d ----------------
__global__ __launch_bounds__(256) void agg_kernel(const unsigned short* __restrict__ h16,
                                                  const int* __restrict__ offs,
                                                  const int* __restrict__ csr_src,
                                                  const float* __restrict__ s,
                                                  const float* __restrict__ d,
                                                  const float* __restrict__ bias,
                                                  unsigned short* __restrict__ hout16,
                                                  const float* __restrict__ wv_s,
                                                  const float* __restrict__ wv_d,
                                                  float* __restrict__ s_next,
                                                  float* __restrict__ d_next,
                                                  int do_sd){
  __shared__ int2 meta[4][112];
  const int wv = threadIdx.x >> 6;
  const int node = blockIdx.x*4 + wv;
  const int lane = threadIdx.x & 63;
  if (node >= NN) return;
  const float d_i = d[node];
  const int beg = offs[node], end = offs[node+1];
  const int deg = end - beg;
  const bool fast = (deg <= MAXD);          // wave-uniform

  // pass A: e_j, online softmax stats
  float m_l = -1e30f, s_l = 0.f;
  for (int j = lane; j < deg; j += 64){
    int sj = csr_src[beg + j];
    float e = lrelu(s[sj] + d_i);
    if (fast) meta[wv][j] = make_int2(sj, __float_as_int(e));
    float nm = fmaxf(m_l, e);
    s_l = s_l*__expf(m_l - nm) + __expf(e - nm);
    m_l = nm;
  }
  #pragma unroll
  for (int off = 32; off > 0; off >>= 1){
    float om = __shfl_xor(m_l, off);
    float os = __shfl_xor(s_l, off);
    float nm = fmaxf(m_l, om);
    s_l = s_l*__expf(m_l - nm) + os*__expf(om - nm);
    m_l = nm;
  }
  const float e0 = lrelu(s[node] + d_i);    // self loop
  const float m_i = fmaxf(m_l, e0);
  const float inv_den = 1.f / (s_l*__expf(m_l - m_i) + __expf(e0 - m_i));
  const float w0 = __expf(e0 - m_i) * inv_den;

  const int half = lane >> 5;
  const int c    = lane & 31;
  const u16x8* h8 = (const u16x8*)h16;

  float acc[8];
  #pragma unroll
  for (int i = 0; i < 8; i++) acc[i] = 0.f;

  if (fast){
    const int n_s = deg + 1;                // + self loop
    const int np  = (n_s + 7) & ~7;
    for (int j = lane; j < np; j += 64){
      int sj; float w;
      if (j < deg){
        int2 mv = meta[wv][j];
        sj = mv.x;
        w = __expf(__int_as_float(mv.y) - m_i) * inv_den;
      } else if (j == deg){ sj = node; w = w0; }
      else { sj = 0; w = 0.f; }
      meta[wv][j] = make_int2(sj, __float_as_int(w));
    }
    for (int eb = 0; eb < np; eb += 8){
      int2 m0 = meta[wv][eb + half];
      int2 m1 = meta[wv][eb + 2 + half];
      int2 m2 = meta[wv][eb + 4 + half];
      int2 m3 = meta[wv][eb + 6 + half];
      u16x8 h0 = h8[(size_t)m0.x*32 + c];
      u16x8 h1 = h8[(size_t)m1.x*32 + c];
      u16x8 h2 = h8[(size_t)m2.x*32 + c];
      u16x8 h3 = h8[(size_t)m3.x*32 + c];
      float w0f = __int_as_float(m0.y), w1f = __int_as_float(m1.y);
      float w2f = __int_as_float(m2.y), w3f = __int_as_float(m3.y);
      #pragma unroll
      for (int i = 0; i < 8; i++) acc[i] += w0f * b2f(h0[i]);
      #pragma unroll
      for (int i = 0; i < 8; i++) acc[i] += w1f * b2f(h1[i]);
      #pragma unroll
      for (int i = 0; i < 8; i++) acc[i] += w2f * b2f(h2[i]);
      #pragma unroll
      for (int i = 0; i < 8; i++) acc[i] += w3f * b2f(h3[i]);
    }
  } else {
    if (half == 0){
      u16x8 hv = h8[(size_t)node*32 + c];
      #pragma unroll
      for (int i = 0; i < 8; i++) acc[i] += w0 * b2f(hv[i]);
    }
    for (int eb = beg; eb < end; eb += 4){
      int e1 = eb + half;
      int e2 = e1 + 2;
      int sa = csr_src[min(e1, end-1)];
      int sb = csr_src[min(e2, end-1)];
      float wa = (e1 < end) ? __expf(lrelu(s[sa] + d_i) - m_i) * inv_den : 0.f;
      float wb = (e2 < end) ? __expf(lrelu(s[sb] + d_i) - m_i) * inv_den : 0.f;
      u16x8 ha = h8[(size_t)sa*32 + c];
      u16x8 hb = h8[(size_t)sb*32 + c];
      #pragma unroll
      for (int i = 0; i < 8; i++) acc[i] += wa * b2f(ha[i]);
      #pragma unroll
      for (int i = 0; i < 8; i++) acc[i] += wb * b2f(hb[i]);
    }
  }

  // merge halves
  #pragma unroll
  for (int i = 0; i < 8; i++) acc[i] += __shfl_xor(acc[i], 32);

  // bias + relu
  const float4* bb = (const float4*)(bias + c*8);
  float4 b0 = bb[0], b1 = bb[1];
  acc[0] = fmaxf(acc[0] + b0.x, 0.f); acc[1] = fmaxf(acc[1] + b0.y, 0.f);
  acc[2] = fmaxf(acc[2] + b0.z, 0.f); acc[3] = fmaxf(acc[3] + b0.w, 0.f);
  acc[4] = fmaxf(acc[4] + b1.x, 0.f); acc[5] = fmaxf(acc[5] + b1.y, 0.f);
  acc[6] = fmaxf(acc[6] + b1.z, 0.f); acc[7] = fmaxf(acc[7] + b1.w, 0.f);

  if (half == 0){
    u16x8 o;
    #pragma unroll
    for (int i = 0; i < 8; i++) o[i] = f2b(acc[i]);
    ((u16x8*)hout16)[(size_t)node*32 + c] = o;
  }

  // next-layer s/d from the fp32 acc (pre-bf16-rounding)
  if (do_sd){
    const float4* ws4 = (const float4*)(wv_s + c*8);
    const float4* wd4 = (const float4*)(wv_d + c*8);
    float4 s0 = ws4[0], s1 = ws4[1], dd0 = wd4[0], dd1 = wd4[1];
    float ps = acc[0]*s0.x + acc[1]*s0.y + acc[2]*s0.z + acc[3]*s0.w
             + acc[4]*s1.x + acc[5]*s1.y + acc[6]*s1.z + acc[7]*s1.w;
    float pd = acc[0]*dd0.x + acc[1]*dd0.y + acc[2]*dd0.z + acc[3]*dd0.w
             + acc[4]*dd1.x + acc[5]*dd1.y + acc[6]*dd1.z + acc[7]*dd1.w;
    #pragma unroll
    for (int o = 16; o > 0; o >>= 1){
      ps += __shfl_xor(ps, o);
      pd += __shfl_xor(pd, o);
    }
    if (lane == 0){ s_next[node] = ps; d_next[node] = pd; }
  }
}

// ---------------- global add pool (batch sorted), bf16 input ----------------
__device__ __forceinline__ int lbound(const int* a, int n, int v){
  int lo = 0, hi = n;
  while (lo < hi){ int mid = (lo + hi) >> 1; if (a[mid] < v) lo = mid + 1; else hi = mid; }
  return lo;
}

__global__ __launch_bounds__(256) void pool_kernel(const unsigned short* __restrict__ h16,
                                                   const int* __restrict__ batch,
                                                   float* __restrict__ pooled){
  int g = blockIdx.x, split = blockIdx.y, t = threadIdx.x;
  int lo = lbound(batch, NN, g);
  int hi = lbound(batch, NN, g + 1);
  int len = hi - lo;
  int chunk = (len + 15) >> 4;
  int b  = lo + split*chunk;
  int e2 = min(hi, b + chunk);
  float acc = 0.f;
  for (int i = b; i < e2; i++) acc += b2f(h16[(size_t)i*D_H + t]);
  atomicAdd(&pooled[g*D_H + t], acc);
}

// ---------------- final FC: [64,256] @ [256,64] + b ----------------
__global__ __launch_bounds__(64) void fc_kernel(const float* __restrict__ pooled,
                                                const float* __restrict__ fcW,
                                                const float* __restrict__ fcb,
                                                float* __restrict__ out){
  int g = blockIdx.x, o = threadIdx.x;
  float acc = fcb[o];
  for (int k = 0; k < D_H; k++) acc += pooled[g*D_H + k] * fcW[k*D_OUT + o];
  out[g*D_OUT + o] = acc;
}

extern "C" void kernel_launch(void* const* d_in, const int* in_sizes, int n_in,
                              void* d_out, int out_size, void* d_ws, size_t ws_size,
                              hipStream_t stream){
  const float* x     = (const float*)d_in[0];
  const int*   ei    = (const int*)d_in[1];
  const int*   batch = (const int*)d_in[2];
  const float* W1  = (const float*)d_in[3];
  const float* as1 = (const float*)d_in[4];
  const float* ad1 = (const float*)d_in[5];
  const float* b1  = (const float*)d_in[6];
  const float* W2  = (const float*)d_in[7];
  const float* as2 = (const float*)d_in[8];
  const float* ad2 = (const float*)d_in[9];
  const float* b2  = (const float*)d_in[10];
  const float* W3  = (const float*)d_in[11];
  const float* as3 = (const float*)d_in[12];
  const float* ad3 = (const float*)d_in[13];
  const float* b3  = (const float*)d_in[14];
  const float* fcW = (const float*)d_in[15];
  const float* fcb = (const float*)d_in[16];

  const int* src = ei;
  const int* dst = ei + NE;

  char* p = (char*)d_ws;
  auto alloc = [&](size_t bytes) -> void* {
    void* r = (void*)p;
    p += (bytes + 255) & ~(size_t)255;
    return r;
  };
  unsigned short* h_a16 = (unsigned short*)alloc((size_t)NN*D_H*2);
  unsigned short* h_b16 = (unsigned short*)alloc((size_t)NN*D_H*2);
  unsigned short* xb    = (unsigned short*)alloc((size_t)NN*D_IN*2);
  unsigned short* Wt0   = (unsigned short*)alloc((size_t)256*D_IN*2);
  unsigned short* Wt1   = (unsigned short*)alloc((size_t)256*256*2);
  unsigned short* Wt2   = (unsigned short*)alloc((size_t)256*256*2);
  float* sA     = (float*)alloc((size_t)NN*4);
  float* dA     = (float*)alloc((size_t)NN*4);
  float* sB     = (float*)alloc((size_t)NN*4);
  float* dB     = (float*)alloc((size_t)NN*4);
  float* wv     = (float*)alloc((size_t)1280*4);
  int* deg      = (int*)alloc((size_t)NN*4);
  int* offs     = (int*)alloc((size_t)(NN+1)*4);
  int* cursor   = (int*)alloc((size_t)NN*4);
  int* bsum     = (int*)alloc((size_t)256*4);
  int* csr      = (int*)alloc((size_t)NE*4);
  float* pooled = (float*)alloc((size_t)NG*D_H*4);

  const int nblk = (NN + 255)/256;   // 196

  hipMemsetAsync(deg, 0, NN*sizeof(int), stream);
  hipMemsetAsync(pooled, 0, NG*D_H*sizeof(float), stream);

  // cast x + count degrees (fused)
  prep_kernel<<<(NN*D_IN/4 + 255)/256, 256, 0, stream>>>(x, xb, dst, deg);
  // cast weights (fragment-packed) + wv vectors
  cast_wt_all<<<643, 256, 0, stream>>>(W1, W2, W3, as1, ad1, as2, ad2, as3, ad3,
                                       Wt0, Wt1, Wt2, wv);
  // CSR
  scan_bsum<<<nblk, 256, 0, stream>>>(deg, bsum);
  scan_offs<<<nblk, 256, 0, stream>>>(deg, bsum, offs, cursor, nblk);
  scatter_csr<<<(NE + 255)/256, 256, 0, stream>>>(src, dst, cursor, csr);

  // s1/d1 from xb
  sd1_kernel<<<(NN*64 + 255)/256, 256, 0, stream>>>(xb, wv, sA, dA);

  const int mgrid = (NN + 127)/128;   // 391
  const int agrid = (NN + 3)/4;

  // layer 1
  gemm_bf16<128><<<dim3(mgrid, 2), 256, 0, stream>>>(xb, Wt0, h_a16);
  agg_kernel<<<agrid, 256, 0, stream>>>(h_a16, offs, csr, sA, dA, b1, h_b16,
                                        wv + 256, wv + 512, sB, dB, 1);
  // layer 2
  gemm_bf16<256><<<dim3(mgrid, 2), 256, 0, stream>>>(h_b16, Wt1, h_a16);
  agg_kernel<<<agrid, 256, 0, stream>>>(h_a16, offs, csr, sB, dB, b2, h_b16,
                                        wv + 768, wv + 1024, sA, dA, 1);
  // layer 3
  gemm_bf16<256><<<dim3(mgrid, 2), 256, 0, stream>>>(h_b16, Wt2, h_a16);
  agg_kernel<<<agrid, 256, 0, stream>>>(h_a16, offs, csr, sA, dA, b3, h_b16,
                                        (const float*)nullptr, (const float*)nullptr,
                                        (float*)nullptr, (float*)nullptr, 0);

  pool_kernel<<<dim3(NG, 16), 256, 0, stream>>>(h_b16, batch, pooled);
  fc_kernel<<<NG, 64, 0, stream>>>(pooled, fcW, fcb, (float*)d_out);
}

// Round 6
// 480.867 us; speedup vs baseline: 2.6121x; 1.0213x over previous
//
#include <hip/hip_runtime.h>

#define NN 50000
#define NE 800000
#define D_IN 128
#define D_H 256
#define D_OUT 64
#define NG 64
#define MAXD 100   // fast-path degree cap

typedef _Float16 f16;
typedef _Float16 f16x8 __attribute__((ext_vector_type(8)));
typedef _Float16 f16x2 __attribute__((ext_vector_type(2)));
typedef unsigned short u16x8 __attribute__((ext_vector_type(8)));
typedef float f32x4 __attribute__((ext_vector_type(4)));

__device__ __forceinline__ float lrelu(float x){ return x > 0.f ? x : 0.2f*x; }

__device__ __forceinline__ unsigned short f2h(float f){
  f16 h = (f16)f;
  return __builtin_bit_cast(unsigned short, h);
}
__device__ __forceinline__ float h2f(unsigned short b){
  return (float)__builtin_bit_cast(f16, b);
}

// acc += h * w  (4x v_pk_fma_f16)
__device__ __forceinline__ void pkfma(f16x8& acc, u16x8 hraw, f16x2 w2){
  f16x8 hv = __builtin_bit_cast(f16x8, hraw);
  f16x2* a2 = (f16x2*)&acc;
  const f16x2* h2p = (const f16x2*)&hv;
  #pragma unroll
  for (int k = 0; k < 4; k++) a2[k] += h2p[k] * w2;
}

// ---------------- prep: cast x to f16 + degree count ----------------
__global__ __launch_bounds__(256) void prep_kernel(const float* __restrict__ x,
                                                   unsigned short* __restrict__ xb,
                                                   const int* __restrict__ dst,
                                                   int* __restrict__ deg){
  int gid = blockIdx.x*256 + threadIdx.x;
  if (gid < NN*D_IN/4){
    float4 v = ((const float4*)x)[gid];
    ushort4 o = { f2h(v.x), f2h(v.y), f2h(v.z), f2h(v.w) };
    ((ushort4*)xb)[gid] = o;
  }
  if (gid < NE) atomicAdd(&deg[dst[gid]], 1);
}

// W [K][256] row-major -> Wt packed in MFMA B-fragment order
__device__ __forceinline__ void cast_one_wt(const float* W, unsigned short* Wt, int K, int idx){
  int k = idx >> 8, n = idx & 255;
  int grp = (n >> 4)*(K >> 5) + (k >> 5);
  int within = ((((k >> 3) & 3) << 4) | (n & 15)) * 8 + (k & 7);
  Wt[grp*512 + within] = f2h(W[idx]);
}

__global__ __launch_bounds__(256) void cast_wt_all(const float* __restrict__ W1,
                                                   const float* __restrict__ W2,
                                                   const float* __restrict__ W3,
                                                   const float* __restrict__ as1,
                                                   const float* __restrict__ ad1,
                                                   const float* __restrict__ as2,
                                                   const float* __restrict__ ad2,
                                                   const float* __restrict__ as3,
                                                   const float* __restrict__ ad3,
                                                   unsigned short* __restrict__ Wt0,
                                                   unsigned short* __restrict__ Wt1,
                                                   unsigned short* __restrict__ Wt2,
                                                   float* __restrict__ wv){
  int b = blockIdx.x;
  if (b < 640){
    int e = b*256 + threadIdx.x;
    if (e < 32768)        cast_one_wt(W1, Wt0, 128, e);
    else if (e < 98304)   cast_one_wt(W2, Wt1, 256, e - 32768);
    else                  cast_one_wt(W3, Wt2, 256, e - 98304);
  } else {
    int L = b - 640;
    const float* W  = (L==0) ? W1 : ((L==1) ? W2 : W3);
    const float* av = (L==0) ? as1 : ((L==1) ? as2 : as3);
    const float* dv = (L==0) ? ad1 : ((L==1) ? ad2 : ad3);
    int K   = (L==0) ? 128 : 256;
    int off = (L==0) ? 0 : ((L==1) ? 256 : 768);
    int k = threadIdx.x;
    if (k < K){
      float ps = 0.f, pd = 0.f;
      for (int n = 0; n < 256; n += 4){
        float4 w  = *(const float4*)(W + k*256 + n);
        float4 a  = *(const float4*)(av + n);
        float4 d2 = *(const float4*)(dv + n);
        ps += w.x*a.x + w.y*a.y + w.z*a.z + w.w*a.w;
        pd += w.x*d2.x + w.y*d2.y + w.z*d2.z + w.w*d2.w;
      }
      wv[off + k]     = ps;
      wv[off + K + k] = pd;
    }
  }
}

// ---------------- CSR build ----------------
__global__ __launch_bounds__(256) void scan_bsum(const int* __restrict__ deg,
                                                 int* __restrict__ bsum){
  __shared__ int sm[256];
  int b = blockIdx.x, t = threadIdx.x;
  int gid = b*256 + t;
  sm[t] = (gid < NN) ? deg[gid] : 0;
  __syncthreads();
  for (int off = 128; off > 0; off >>= 1){
    if (t < off) sm[t] += sm[t+off];
    __syncthreads();
  }
  if (t == 0) bsum[b] = sm[0];
}

__global__ __launch_bounds__(256) void scan_offs(const int* __restrict__ deg,
                                                 const int* __restrict__ bsum,
                                                 int* __restrict__ offs,
                                                 int* __restrict__ cursor,
                                                 int nblk){
  __shared__ int sb[256];
  __shared__ int sm[256];
  int b = blockIdx.x, t = threadIdx.x;
  sb[t] = (t < nblk) ? bsum[t] : 0;
  __syncthreads();
  for (int off = 1; off < 256; off <<= 1){
    int v = (t >= off) ? sb[t-off] : 0;
    __syncthreads();
    sb[t] += v;
    __syncthreads();
  }
  int base = (b == 0) ? 0 : sb[b-1];
  int gid = b*256 + t;
  int v = (gid < NN) ? deg[gid] : 0;
  sm[t] = v;
  __syncthreads();
  for (int off = 1; off < 256; off <<= 1){
    int u = (t >= off) ? sm[t-off] : 0;
    __syncthreads();
    sm[t] += u;
    __syncthreads();
  }
  int incl = sm[t], excl = incl - v;
  if (gid < NN){ offs[gid] = base + excl; cursor[gid] = base + excl; }
  if (gid == NN-1) offs[NN] = base + incl;
}

__global__ void scatter_csr(const int* __restrict__ src, const int* __restrict__ dst,
                            int* __restrict__ cursor, int* __restrict__ csr_src){
  int e = blockIdx.x*256 + threadIdx.x;
  if (e < NE){
    int d = dst[e];
    int pos = atomicAdd(&cursor[d], 1);
    csr_src[pos] = src[e];
  }
}

// ---------------- f16 MFMA GEMM: full-K LDS panel, one barrier, LDS-staged C ----------------
template<int K>
__global__ __launch_bounds__(256) void gemm_f16(const unsigned short* __restrict__ A,
                                                const unsigned short* __restrict__ Wt,
                                                unsigned short* __restrict__ C16){
  constexpr int CH  = K/8;
  constexpr int SH  = (K > 132) ? K : 132;
  __shared__ unsigned short As[128*SH];
  const int t = threadIdx.x;
  const int bm = blockIdx.x * 128;
  const int bn = blockIdx.y * 128;
  const int wave = t >> 6, lane = t & 63;
  const int wm = (wave >> 1) * 64, wn = (wave & 1) * 64;
  const int l15 = lane & 15, quad = lane >> 4;

  {
    const int c  = t & (CH-1);
    const int r0 = t / CH;
    constexpr int NRG = 256/CH;
    const int p = c ^ (r0 & 7);
    #pragma unroll
    for (int g = 0; g < 128/NRG; g++){
      int row = r0 + g*NRG;
      int grow = bm + row;
      u16x8 v = {0,0,0,0,0,0,0,0};
      if (grow < NN) v = *(const u16x8*)(A + (size_t)grow*K + c*8);
      *(u16x8*)(&As[row*K + p*8]) = v;
    }
  }
  __syncthreads();

  f32x4 acc[4][4];
  #pragma unroll
  for (int i = 0; i < 4; i++)
    #pragma unroll
    for (int j = 0; j < 4; j++){
      f32x4 z = {0.f, 0.f, 0.f, 0.f};
      acc[i][j] = z;
    }

  #pragma unroll
  for (int ks = 0; ks < K/32; ks++){
    f16x8 af[4];
    const int pc = ((ks*4 + quad) ^ (l15 & 7)) * 8;
    #pragma unroll
    for (int i = 0; i < 4; i++)
      af[i] = *(const f16x8*)(&As[(wm + i*16 + l15)*K + pc]);
    #pragma unroll
    for (int j = 0; j < 4; j++){
      int nb = ((bn + wn) >> 4) + j;
      f16x8 bfr = *(const f16x8*)(Wt + ((size_t)(nb*(K>>5) + ks))*512 + lane*8);
      #pragma unroll
      for (int i = 0; i < 4; i++)
        acc[i][j] = __builtin_amdgcn_mfma_f32_16x16x32_f16(af[i], bfr, acc[i][j], 0, 0, 0);
    }
  }

  __syncthreads();
  #pragma unroll
  for (int i = 0; i < 4; i++)
    #pragma unroll
    for (int j = 0; j < 4; j++)
      #pragma unroll
      for (int r = 0; r < 4; r++)
        As[(wm + i*16 + quad*4 + r)*132 + wn + j*16 + l15] = f2h(acc[i][j][r]);
  __syncthreads();
  {
    const int rl = t >> 1, hc = (t & 1)*64;
    const int grow = bm + rl;
    if (grow < NN){
      #pragma unroll
      for (int u = 0; u < 8; u++){
        u16x8 v = *(const u16x8*)(&As[rl*132 + hc + u*8]);
        *(u16x8*)(C16 + (size_t)grow*256 + bn + hc + u*8) = v;
      }
    }
  }
}

// ---------------- s1/d1 = xb @ wv1 (K=128) ----------------
__global__ __launch_bounds__(256) void sd1_kernel(const unsigned short* __restrict__ xb,
                                                  const float* __restrict__ wv,
                                                  float* __restrict__ s, float* __restrict__ d){
  int node = (blockIdx.x*256 + threadIdx.x) >> 6;
  int lane = threadIdx.x & 63;
  if (node >= NN) return;
  ushort2 xv = ((const ushort2*)xb)[(size_t)node*64 + lane];
  float2 ws = ((const float2*)(wv))[lane];
  float2 wd = ((const float2*)(wv + 128))[lane];
  float x0 = h2f(xv.x), x1 = h2f(xv.y);
  float ps = x0*ws.x + x1*ws.y;
  float pd = x0*wd.x + x1*wd.y;
  #pragma unroll
  for (int o = 32; o > 0; o >>= 1){
    ps += __shfl_down(ps, o);
    pd += __shfl_down(pd, o);
  }
  if (lane == 0){ s[node] = ps; d[node] = pd; }
}

// ---------------- fused softmax + aggregation + next-layer s/d ----------------
__global__ __launch_bounds__(256) void agg_kernel(const unsigned short* __restrict__ h16,
                                                  const int* __restrict__ offs,
                                                  const int* __restrict__ csr_src,
                                                  const float* __restrict__ s,
                                                  const float* __restrict__ d,
                                                  const float* __restrict__ bias,
                                                  unsigned short* __restrict__ hout16,
                                                  const float* __restrict__ wv_s,
                                                  const float* __restrict__ wv_d,
                                                  float* __restrict__ s_next,
                                                  float* __restrict__ d_next,
                                                  int do_sd){
  __shared__ int2 meta[4][112];
  const int wv = threadIdx.x >> 6;
  const int node = blockIdx.x*4 + wv;
  const int lane = threadIdx.x & 63;
  if (node >= NN) return;
  const float d_i = d[node];
  const int beg = offs[node], end = offs[node+1];
  const int deg = end - beg;
  const bool fast = (deg <= MAXD);

  // pass A: e_j, online softmax stats
  float m_l = -1e30f, s_l = 0.f;
  for (int j = lane; j < deg; j += 64){
    int sj = csr_src[beg + j];
    float e = lrelu(s[sj] + d_i);
    if (fast) meta[wv][j] = make_int2(sj, __float_as_int(e));
    float nm = fmaxf(m_l, e);
    s_l = s_l*__expf(m_l - nm) + __expf(e - nm);
    m_l = nm;
  }
  #pragma unroll
  for (int off = 32; off > 0; off >>= 1){
    float om = __shfl_xor(m_l, off);
    float os = __shfl_xor(s_l, off);
    float nm = fmaxf(m_l, om);
    s_l = s_l*__expf(m_l - nm) + os*__expf(om - nm);
    m_l = nm;
  }
  const float e0 = lrelu(s[node] + d_i);
  const float m_i = fmaxf(m_l, e0);
  const float inv_den = 1.f / (s_l*__expf(m_l - m_i) + __expf(e0 - m_i));
  const float w0 = __expf(e0 - m_i) * inv_den;

  const int half = lane >> 5;
  const int c    = lane & 31;
  const u16x8* h8 = (const u16x8*)h16;

  f16x8 acc8 = {0,0,0,0,0,0,0,0};

  if (fast){
    const int n_s = deg + 1;
    const int np  = (n_s + 7) & ~7;
    // pass B: e -> packed f16x2 weight {w,w}; append self; pad with 0
    for (int j = lane; j < np; j += 64){
      int sj; float w;
      if (j < deg){
        int2 mv = meta[wv][j];
        sj = mv.x;
        w = __expf(__int_as_float(mv.y) - m_i) * inv_den;
      } else if (j == deg){ sj = node; w = w0; }
      else { sj = 0; w = 0.f; }
      f16 wh = (f16)w;
      f16x2 wp = {wh, wh};
      meta[wv][j] = make_int2(sj, __builtin_bit_cast(int, wp));
    }
    for (int eb = 0; eb < np; eb += 8){
      int2 m0 = meta[wv][eb + half];
      int2 m1 = meta[wv][eb + 2 + half];
      int2 m2 = meta[wv][eb + 4 + half];
      int2 m3 = meta[wv][eb + 6 + half];
      u16x8 h0 = h8[(size_t)m0.x*32 + c];
      u16x8 h1 = h8[(size_t)m1.x*32 + c];
      u16x8 h2 = h8[(size_t)m2.x*32 + c];
      u16x8 h3 = h8[(size_t)m3.x*32 + c];
      pkfma(acc8, h0, __builtin_bit_cast(f16x2, m0.y));
      pkfma(acc8, h1, __builtin_bit_cast(f16x2, m1.y));
      pkfma(acc8, h2, __builtin_bit_cast(f16x2, m2.y));
      pkfma(acc8, h3, __builtin_bit_cast(f16x2, m3.y));
    }
  } else {
    if (half == 0){
      f16 wh = (f16)w0;
      f16x2 wp = {wh, wh};
      pkfma(acc8, h8[(size_t)node*32 + c], wp);
    }
    for (int eb = beg; eb < end; eb += 4){
      int e1 = eb + half;
      int e2 = e1 + 2;
      int sa = csr_src[min(e1, end-1)];
      int sb = csr_src[min(e2, end-1)];
      float wa = (e1 < end) ? __expf(lrelu(s[sa] + d_i) - m_i) * inv_den : 0.f;
      float wb = (e2 < end) ? __expf(lrelu(s[sb] + d_i) - m_i) * inv_den : 0.f;
      f16 wah = (f16)wa, wbh = (f16)wb;
      f16x2 wap = {wah, wah}, wbp = {wbh, wbh};
      pkfma(acc8, h8[(size_t)sa*32 + c], wap);
      pkfma(acc8, h8[(size_t)sb*32 + c], wbp);
    }
  }

  // to f32, merge halves
  float acc[8];
  #pragma unroll
  for (int i = 0; i < 8; i++) acc[i] = (float)acc8[i];
  #pragma unroll
  for (int i = 0; i < 8; i++) acc[i] += __shfl_xor(acc[i], 32);

  // bias + relu
  const float4* bb = (const float4*)(bias + c*8);
  float4 b0 = bb[0], b1 = bb[1];
  acc[0] = fmaxf(acc[0] + b0.x, 0.f); acc[1] = fmaxf(acc[1] + b0.y, 0.f);
  acc[2] = fmaxf(acc[2] + b0.z, 0.f); acc[3] = fmaxf(acc[3] + b0.w, 0.f);
  acc[4] = fmaxf(acc[4] + b1.x, 0.f); acc[5] = fmaxf(acc[5] + b1.y, 0.f);
  acc[6] = fmaxf(acc[6] + b1.z, 0.f); acc[7] = fmaxf(acc[7] + b1.w, 0.f);

  if (half == 0){
    u16x8 o;
    #pragma unroll
    for (int i = 0; i < 8; i++) o[i] = f2h(acc[i]);
    ((u16x8*)hout16)[(size_t)node*32 + c] = o;
  }

  if (do_sd){
    const float4* ws4 = (const float4*)(wv_s + c*8);
    const float4* wd4 = (const float4*)(wv_d + c*8);
    float4 s0 = ws4[0], s1 = ws4[1], dd0 = wd4[0], dd1 = wd4[1];
    float ps = acc[0]*s0.x + acc[1]*s0.y + acc[2]*s0.z + acc[3]*s0.w
             + acc[4]*s1.x + acc[5]*s1.y + acc[6]*s1.z + acc[7]*s1.w;
    float pd = acc[0]*dd0.x + acc[1]*dd0.y + acc[2]*dd0.z + acc[3]*dd0.w
             + acc[4]*dd1.x + acc[5]*dd1.y + acc[6]*dd1.z + acc[7]*dd1.w;
    #pragma unroll
    for (int o = 16; o > 0; o >>= 1){
      ps += __shfl_xor(ps, o);
      pd += __shfl_xor(pd, o);
    }
    if (lane == 0){ s_next[node] = ps; d_next[node] = pd; }
  }
}

// ---------------- global add pool (batch sorted), f16 input ----------------
__device__ __forceinline__ int lbound(const int* a, int n, int v){
  int lo = 0, hi = n;
  while (lo < hi){ int mid = (lo + hi) >> 1; if (a[mid] < v) lo = mid + 1; else hi = mid; }
  return lo;
}

__global__ __launch_bounds__(256) void pool_kernel(const unsigned short* __restrict__ h16,
                                                   const int* __restrict__ batch,
                                                   float* __restrict__ pooled){
  int g = blockIdx.x, split = blockIdx.y, t = threadIdx.x;
  int lo = lbound(batch, NN, g);
  int hi = lbound(batch, NN, g + 1);
  int len = hi - lo;
  int chunk = (len + 15) >> 4;
  int b  = lo + split*chunk;
  int e2 = min(hi, b + chunk);
  float acc = 0.f;
  for (int i = b; i < e2; i++) acc += h2f(h16[(size_t)i*D_H + t]);
  atomicAdd(&pooled[g*D_H + t], acc);
}

// ---------------- final FC ----------------
__global__ __launch_bounds__(64) void fc_kernel(const float* __restrict__ pooled,
                                                const float* __restrict__ fcW,
                                                const float* __restrict__ fcb,
                                                float* __restrict__ out){
  int g = blockIdx.x, o = threadIdx.x;
  float acc = fcb[o];
  for (int k = 0; k < D_H; k++) acc += pooled[g*D_H + k] * fcW[k*D_OUT + o];
  out[g*D_OUT + o] = acc;
}

extern "C" void kernel_launch(void* const* d_in, const int* in_sizes, int n_in,
                              void* d_out, int out_size, void* d_ws, size_t ws_size,
                              hipStream_t stream){
  const float* x     = (const float*)d_in[0];
  const int*   ei    = (const int*)d_in[1];
  const int*   batch = (const int*)d_in[2];
  const float* W1  = (const float*)d_in[3];
  const float* as1 = (const float*)d_in[4];
  const float* ad1 = (const float*)d_in[5];
  const float* b1  = (const float*)d_in[6];
  const float* W2  = (const float*)d_in[7];
  const float* as2 = (const float*)d_in[8];
  const float* ad2 = (const float*)d_in[9];
  const float* b2  = (const float*)d_in[10];
  const float* W3  = (const float*)d_in[11];
  const float* as3 = (const float*)d_in[12];
  const float* ad3 = (const float*)d_in[13];
  const float* b3  = (const float*)d_in[14];
  const float* fcW = (const float*)d_in[15];
  const float* fcb = (const float*)d_in[16];

  const int* src = ei;
  const int* dst = ei + NE;

  char* p = (char*)d_ws;
  auto alloc = [&](size_t bytes) -> void* {
    void* r = (void*)p;
    p += (bytes + 255) & ~(size_t)255;
    return r;
  };
  unsigned short* h_a16 = (unsigned short*)alloc((size_t)NN*D_H*2);
  unsigned short* h_b16 = (unsigned short*)alloc((size_t)NN*D_H*2);
  unsigned short* xb    = (unsigned short*)alloc((size_t)NN*D_IN*2);
  unsigned short* Wt0   = (unsigned short*)alloc((size_t)256*D_IN*2);
  unsigned short* Wt1   = (unsigned short*)alloc((size_t)256*256*2);
  unsigned short* Wt2   = (unsigned short*)alloc((size_t)256*256*2);
  float* sA     = (float*)alloc((size_t)NN*4);
  float* dA     = (float*)alloc((size_t)NN*4);
  float* sB     = (float*)alloc((size_t)NN*4);
  float* dB     = (float*)alloc((size_t)NN*4);
  float* wv     = (float*)alloc((size_t)1280*4);
  int* deg      = (int*)alloc((size_t)NN*4);
  int* offs     = (int*)alloc((size_t)(NN+1)*4);
  int* cursor   = (int*)alloc((size_t)NN*4);
  int* bsum     = (int*)alloc((size_t)256*4);
  int* csr      = (int*)alloc((size_t)NE*4);
  float* pooled = (float*)alloc((size_t)NG*D_H*4);

  const int nblk = (NN + 255)/256;

  hipMemsetAsync(deg, 0, NN*sizeof(int), stream);
  hipMemsetAsync(pooled, 0, NG*D_H*sizeof(float), stream);

  prep_kernel<<<(NN*D_IN/4 + 255)/256, 256, 0, stream>>>(x, xb, dst, deg);
  cast_wt_all<<<643, 256, 0, stream>>>(W1, W2, W3, as1, ad1, as2, ad2, as3, ad3,
                                       Wt0, Wt1, Wt2, wv);
  scan_bsum<<<nblk, 256, 0, stream>>>(deg, bsum);
  scan_offs<<<nblk, 256, 0, stream>>>(deg, bsum, offs, cursor, nblk);
  scatter_csr<<<(NE + 255)/256, 256, 0, stream>>>(src, dst, cursor, csr);

  sd1_kernel<<<(NN*64 + 255)/256, 256, 0, stream>>>(xb, wv, sA, dA);

  const int mgrid = (NN + 127)/128;
  const int agrid = (NN + 3)/4;

  gemm_f16<128><<<dim3(mgrid, 2), 256, 0, stream>>>(xb, Wt0, h_a16);
  agg_kernel<<<agrid, 256, 0, stream>>>(h_a16, offs, csr, sA, dA, b1, h_b16,
                                        wv + 256, wv + 512, sB, dB, 1);
  gemm_f16<256><<<dim3(mgrid, 2), 256, 0, stream>>>(h_b16, Wt1, h_a16);
  agg_kernel<<<agrid, 256, 0, stream>>>(h_a16, offs, csr, sB, dB, b2, h_b16,
                                        wv + 768, wv + 1024, sA, dA, 1);
  gemm_f16<256><<<dim3(mgrid, 2), 256, 0, stream>>>(h_b16, Wt2, h_a16);
  agg_kernel<<<agrid, 256, 0, stream>>>(h_a16, offs, csr, sA, dA, b3, h_b16,
                                        (const float*)nullptr, (const float*)nullptr,
                                        (float*)nullptr, (float*)nullptr, 0);

  pool_kernel<<<dim3(NG, 16), 256, 0, stream>>>(h_b16, batch, pooled);
  fc_kernel<<<NG, 64, 0, stream>>>(pooled, fcW, fcb, (float*)d_out);
}